// Round 5
// baseline (3390.121 us; speedup 1.0000x reference)
//
#include <hip/hip_runtime.h>
#include <hip/hip_bf16.h>

// ---------------------------------------------------------------------------
// MessagePassing (e3nn-style scalar conv, 2 layers) on MI355X.
// Inputs f32 (indices int32) in dict order. OUTPUT IS FLOAT32 (reference
// output dtype): d_out = nf[50000*32] ++ ea[800000*4], f32.
// Round 5: round-2 math, f32 output. d_out doubles as scratch:
//   nf region holds lin1-x (f32) during each layer (final write last),
//   ea region holds the layer0->1 edge_attr (f32, overwritten by layer 1).
// ws (12.8 MB): agg f32 [1.6M] | inter-layer nf f32 [1.6M] | f0t [2048].
// ---------------------------------------------------------------------------

namespace {
constexpr int NN = 50000;
constexpr int NE = 800000;

constexpr long OFF_AGG = 0;        // f32 [50000*32]
constexpr long OFF_NF  = 1600000;  // f32 [50000*32]
constexpr long OFF_F0T = 3200000;  // f32 [2][64][16]
}

// -------------------------- fc_w0 transpose ---------------------------------
__global__ void k_f0t(const float* __restrict__ f0, float* __restrict__ d) {
    int i = blockIdx.x * blockDim.x + threadIdx.x;   // [0, 2048)
    if (i >= 2048) return;
    int l = i >> 10, q = i & 1023;
    int ii = q >> 6, j = q & 63;                     // src [l][ii(16)][j(64)]
    d[l * 1024 + j * 16 + ii] = f0[i];
}

// ------------------- node pre: x = lin1(nf, nattr); zero agg ----------------
__global__ __launch_bounds__(256) void k_node_pre(
        const float* __restrict__ nf, const float* __restrict__ nattr,
        const float* __restrict__ l1w,
        float* __restrict__ xl, float* __restrict__ agg) {
    int n = blockIdx.x * 256 + threadIdx.x;
    if (n >= NN) return;

    float y[8];
    const float4* yp = (const float4*)(nattr + (long)n * 8);
    float4 y0 = yp[0], y1 = yp[1];
    y[0] = y0.x; y[1] = y0.y; y[2] = y0.z; y[3] = y0.w;
    y[4] = y1.x; y[5] = y1.y; y[6] = y1.z; y[7] = y1.w;

    float acc[32];
#pragma unroll
    for (int k = 0; k < 32; k++) acc[k] = 0.f;

    const float4* xp = (const float4*)(nf + (long)n * 32);
    for (int ug = 0; ug < 8; ug++) {
        float4 xq = xp[ug];
        float xs[4] = {xq.x, xq.y, xq.z, xq.w};
#pragma unroll
        for (int uu = 0; uu < 4; uu++) {
            float xu = xs[uu];
            int u = ug * 4 + uu;
#pragma unroll
            for (int v = 0; v < 8; v++) {
                float z = xu * y[v];
                const float* wb = l1w + (u * 8 + v) * 32;
#pragma unroll
                for (int k = 0; k < 32; k++) acc[k] = fmaf(z, wb[k], acc[k]);
            }
        }
    }
    float4* xlp = (float4*)(xl + (long)n * 32);
    float4* agp = (float4*)(agg + (long)n * 32);
    float4 zz; zz.x = zz.y = zz.z = zz.w = 0.f;
#pragma unroll
    for (int g = 0; g < 8; g++) {
        float4 b;
        b.x = acc[4*g]   * 0.0625f; b.y = acc[4*g+1] * 0.0625f;
        b.z = acc[4*g+2] * 0.0625f; b.w = acc[4*g+3] * 0.0625f;
        xlp[g] = b;
        agp[g] = zz;
    }
}

// -------------------------- fused edge kernel -------------------------------
__global__ __launch_bounds__(256) void k_edge(
        const float* __restrict__ esc, const int* __restrict__ srcp,
        const int* __restrict__ dstp, const float* __restrict__ ea_in,
        float* ea_out,                                // may alias ea_in (row-wise)
        const float* __restrict__ xl,
        const float* __restrict__ f0t, const float* __restrict__ f1,
        const float* __restrict__ sew, float* __restrict__ agg) {
    int e = blockIdx.x * 256 + threadIdx.x;
    if (e >= NE) return;

    float es[16];
    const float4* ep = (const float4*)(esc + (long)e * 16);
#pragma unroll
    for (int g = 0; g < 4; g++) {
        float4 q = ep[g];
        es[4*g] = q.x; es[4*g+1] = q.y; es[4*g+2] = q.z; es[4*g+3] = q.w;
    }
    float4 eaq = ((const float4*)ea_in)[e];
    float ea[4] = {eaq.x, eaq.y, eaq.z, eaq.w};

    float t[32];
#pragma unroll
    for (int u = 0; u < 32; u++) t[u] = 0.f;

    for (int j = 0; j < 64; j++) {            // wave-uniform weight rows
        const float* c0 = f0t + j * 16;
        float ha = 0.f;
#pragma unroll
        for (int i = 0; i < 16; i++) ha = fmaf(es[i], c0[i], ha);
        float h = __sinf(ha * 0.25f);
        const float* r = f1 + j * 128;
#pragma unroll
        for (int u = 0; u < 32; u++) {
            float s = fmaf(ea[0], r[4*u], fmaf(ea[1], r[4*u+1],
                      fmaf(ea[2], r[4*u+2], ea[3] * r[4*u+3])));
            t[u] = fmaf(h, s, t[u]);
        }
    }

    int s_ = srcp[e], d_ = dstp[e];
    float ef[32];
    const float4* xp = (const float4*)(xl + (long)s_ * 32);
#pragma unroll
    for (int g = 0; g < 8; g++) {
        float4 xq = xp[g];
        // scale: (1/sqrt(64) from fc) * (1/sqrt(4) from tp_uvu) = 1/16
        ef[4*g+0] = xq.x * t[4*g+0] * 0.0625f;
        ef[4*g+1] = xq.y * t[4*g+1] * 0.0625f;
        ef[4*g+2] = xq.z * t[4*g+2] * 0.0625f;
        ef[4*g+3] = xq.w * t[4*g+3] * 0.0625f;
    }
    // scatter (fold 1/sqrt(NUM_NEIGHBORS) = 1/4)
#pragma unroll
    for (int u = 0; u < 32; u++)
        atomicAdd(&agg[(long)d_ * 32 + u], ef[u] * 0.25f);

    // edge_out = ea + fctp(ef, ea, sce_w)/sqrt(16)
    float eo[4] = {0.f, 0.f, 0.f, 0.f};
#pragma unroll
    for (int u = 0; u < 32; u++) {
        float efu = ef[u];
#pragma unroll
        for (int v = 0; v < 4; v++) {
            float p = efu * ea[v];
            const float* sw = sew + (u * 4 + v) * 4;
#pragma unroll
            for (int k = 0; k < 4; k++) eo[k] = fmaf(p, sw[k], eo[k]);
        }
    }
    constexpr float SCE_SCALE = 0.02209708691f;  // 1/sqrt(128) * 1/sqrt(16)
    float4 o;
    o.x = ea[0] + eo[0] * SCE_SCALE; o.y = ea[1] + eo[1] * SCE_SCALE;
    o.z = ea[2] + eo[2] * SCE_SCALE; o.w = ea[3] + eo[3] * SCE_SCALE;
    ((float4*)ea_out)[e] = o;
}

// --------- node post: sc + lin2 + alpha + combine (+ sin if not last) -------
__global__ __launch_bounds__(256) void k_node_post(
        const float* __restrict__ nf_cur, const float* __restrict__ nattr,
        const float* __restrict__ scw, const float* __restrict__ l2w,
        const float* __restrict__ aw, const float* __restrict__ agg,
        float* __restrict__ nf_next, float* __restrict__ out_nf, int last) {
    int n = blockIdx.x * 256 + threadIdx.x;
    if (n >= NN) return;

    float y[8];
    const float4* yp = (const float4*)(nattr + (long)n * 8);
    float4 y0 = yp[0], y1 = yp[1];
    y[0] = y0.x; y[1] = y0.y; y[2] = y0.z; y[3] = y0.w;
    y[4] = y1.x; y[5] = y1.y; y[6] = y1.z; y[7] = y1.w;

    // node_sc from nf_cur
    float asc[32];
#pragma unroll
    for (int k = 0; k < 32; k++) asc[k] = 0.f;
    {
        const float4* xp = (const float4*)(nf_cur + (long)n * 32);
        for (int ug = 0; ug < 8; ug++) {
            float4 xq = xp[ug];
            float xs[4] = {xq.x, xq.y, xq.z, xq.w};
#pragma unroll
            for (int uu = 0; uu < 4; uu++) {
                float xu = xs[uu];
                int u = ug * 4 + uu;
#pragma unroll
                for (int v = 0; v < 8; v++) {
                    float z = xu * y[v];
                    const float* wa = scw + (u * 8 + v) * 32;
#pragma unroll
                    for (int k = 0; k < 32; k++) asc[k] = fmaf(z, wa[k], asc[k]);
                }
            }
        }
    }
    // lin2 + alpha from agg
    float a2[32]; float aA = 0.f;
#pragma unroll
    for (int k = 0; k < 32; k++) a2[k] = 0.f;
    {
        const float4* ap = (const float4*)(agg + (long)n * 32);
        for (int ug = 0; ug < 8; ug++) {
            float4 aq = ap[ug];
            float as[4] = {aq.x, aq.y, aq.z, aq.w};
#pragma unroll
            for (int uu = 0; uu < 4; uu++) {
                float au = as[uu];
                int u = ug * 4 + uu;
#pragma unroll
                for (int v = 0; v < 8; v++) {
                    float z = au * y[v];
                    const float* wb = l2w + (u * 8 + v) * 32;
#pragma unroll
                    for (int k = 0; k < 32; k++) a2[k] = fmaf(z, wb[k], a2[k]);
                    aA = fmaf(z, aw[u * 8 + v], aA);
                }
            }
        }
    }
    float alpha = aA * 0.0625f;
    if (last) {
#pragma unroll
        for (int k = 0; k < 32; k++) {
            float o = asc[k] * 0.0625f + alpha * (a2[k] * 0.0625f);
            out_nf[(long)n * 32 + k] = o;
        }
    } else {
#pragma unroll
        for (int k = 0; k < 32; k++) {
            float o = asc[k] * 0.0625f + alpha * (a2[k] * 0.0625f);
            nf_next[(long)n * 32 + k] = __sinf(o);
        }
    }
}

// ---------------------------------------------------------------------------
extern "C" void kernel_launch(void* const* d_in, const int* in_sizes, int n_in,
                              void* d_out, int out_size, void* d_ws, size_t ws_size,
                              hipStream_t stream) {
    // Resolve input order (dict vs sorted-keys) from in_sizes[0].
    int I_nf, I_na, I_esrc, I_edst, I_ea, I_esc, I_sc, I_l1, I_l2, I_al, I_se, I_f0, I_f1;
    if (in_sizes[0] == 1600000) {            // dict order
        I_nf=0; I_na=1; I_esrc=2; I_edst=3; I_ea=4; I_esc=5;
        I_sc=6; I_l1=7; I_l2=8; I_al=9; I_se=10; I_f0=11; I_f1=12;
    } else {                                  // sorted keys
        I_al=0; I_ea=1; I_edst=2; I_esc=3; I_esrc=4; I_f0=5; I_f1=6;
        I_l1=7; I_l2=8; I_na=9; I_nf=10; I_sc=11; I_se=12;
    }
    const float* nf_in = (const float*)d_in[I_nf];
    const float* na    = (const float*)d_in[I_na];
    const int*   esrc  = (const int*)d_in[I_esrc];
    const int*   edst  = (const int*)d_in[I_edst];
    const float* ea_in = (const float*)d_in[I_ea];
    const float* escl  = (const float*)d_in[I_esc];
    const float* w_sc  = (const float*)d_in[I_sc];   // [2][32][8][32]
    const float* w_l1  = (const float*)d_in[I_l1];   // [2][32][8][32]
    const float* w_l2  = (const float*)d_in[I_l2];   // [2][32][8][32]
    const float* w_al  = (const float*)d_in[I_al];   // [2][32][8][1]
    const float* w_se  = (const float*)d_in[I_se];   // [2][32][4][4]
    const float* w_f0  = (const float*)d_in[I_f0];   // [2][16][64]
    const float* w_f1  = (const float*)d_in[I_f1];   // [2][64][128]

    float* ws = (float*)d_ws;
    float* out_nf = (float*)d_out;              // f32 [50000*32]
    float* out_ea = out_nf + (long)NN * 32;     // f32 [800000*4]

    k_f0t<<<8, 256, 0, stream>>>(w_f0, ws + OFF_F0T);

    for (int l = 0; l < 2; l++) {
        int last = (l == 1);
        const float* nf_cur = (l == 0) ? nf_in : (ws + OFF_NF);
        const float* ea_cur = (l == 0) ? ea_in : out_ea;

        k_node_pre<<<196, 256, 0, stream>>>(nf_cur, na, w_l1 + l * 8192,
                                            out_nf /*xl scratch*/, ws + OFF_AGG);
        k_edge<<<3125, 256, 0, stream>>>(escl, esrc, edst, ea_cur, out_ea,
                                         out_nf /*xl*/, ws + OFF_F0T + l * 1024,
                                         w_f1 + l * 8192, w_se + l * 512,
                                         ws + OFF_AGG);
        k_node_post<<<196, 256, 0, stream>>>(nf_cur, na, w_sc + l * 8192,
                                             w_l2 + l * 8192, w_al + l * 256,
                                             ws + OFF_AGG, ws + OFF_NF,
                                             out_nf, last);
    }
}

// Round 6
// 1328.886 us; speedup vs baseline: 2.5511x; 2.5511x over previous
//
#include <hip/hip_runtime.h>
#include <hip/hip_bf16.h>

// ---------------------------------------------------------------------------
// MessagePassing (e3nn scalar conv, 2 layers) on MI355X. Inputs f32, out f32.
// Round 6: atomic scatter (812 MB HBM RMW traffic, 10% VALUBusy) replaced by
// CSR + gather. CSR built once (edge_dst layer-invariant). Edge kernel writes
// ef rows bf16 coalesced; gather sums per node. Node kernels: 1 wave per
// k-quarter (wave-uniform weight rows -> scalar loads). Fallback to atomic
// path if ws_size < 68 MB.
// ---------------------------------------------------------------------------

namespace {
constexpr int NN = 50000;
constexpr int NE = 800000;

// float-indexed ws layout
constexpr long OFF_AGG = 0;        // f32 [1,600,000]
constexpr long OFF_NF  = 1600000;  // f32 [1,600,000]
constexpr long OFF_F0T = 3200000;  // f32 [2048]
constexpr long OFF_OFF = 3210000;  // int [50001]  CSR row offsets
constexpr long OFF_CUR = 3260008;  // int [50000]  counters/cursors
constexpr long OFF_EID = 3310016;  // int [800000] CSR edge ids
constexpr long OFF_EF  = 4110016;  // ushort [25,600,000] ef rows (bf16)
constexpr size_t NEED_BYTES = (OFF_EF + 12800000) * 4;  // 67,640,064
}

__device__ __forceinline__ float us2f(unsigned int u) {
    unsigned int x = u << 16; float f;
    __builtin_memcpy(&f, &x, sizeof(f));
    return f;
}
__device__ __forceinline__ unsigned int f2us(float f) {
    __hip_bfloat16 h = __float2bfloat16(f);
    unsigned short s;
    __builtin_memcpy(&s, &h, sizeof(s));
    return (unsigned int)s;
}

// -------------------------- fc_w0 transpose ---------------------------------
__global__ void k_f0t(const float* __restrict__ f0, float* __restrict__ d) {
    int i = blockIdx.x * blockDim.x + threadIdx.x;
    if (i >= 2048) return;
    int l = i >> 10, q = i & 1023;
    int ii = q >> 6, j = q & 63;                     // src [l][ii(16)][j(64)]
    d[l * 1024 + j * 16 + ii] = f0[i];
}

// -------------------------- CSR build ---------------------------------------
__global__ void k_hist(const int* __restrict__ dst, int* __restrict__ cnt) {
    int e = blockIdx.x * 256 + threadIdx.x;
    if (e < NE) atomicAdd(&cnt[dst[e]], 1);
}

__global__ void k_scan(const int* __restrict__ cnt, int* __restrict__ off,
                       int* __restrict__ cur) {
    __shared__ int part[1024];
    int t = threadIdx.x;
    constexpr int CH = 49;                 // 1024*49 >= 50000
    int base = t * CH, s = 0;
    for (int i = 0; i < CH; i++) { int g = base + i; if (g < NN) s += cnt[g]; }
    part[t] = s; __syncthreads();
    for (int d = 1; d < 1024; d <<= 1) {
        int v = (t >= d) ? part[t - d] : 0;
        __syncthreads();
        part[t] += v;
        __syncthreads();
    }
    int run = (t == 0) ? 0 : part[t - 1];
    for (int i = 0; i < CH; i++) {
        int g = base + i;
        if (g < NN) { int c = cnt[g]; off[g] = run; cur[g] = run; run += c; }
    }
    if (t == 1023) off[NN] = run;          // == NE
}

__global__ void k_scatter(const int* __restrict__ dst, int* __restrict__ cur,
                          int* __restrict__ eid) {
    int e = blockIdx.x * 256 + threadIdx.x;
    if (e >= NE) return;
    int pos = atomicAdd(&cur[dst[e]], 1);
    eid[pos] = e;
}

// ------------- node pre: x = lin1(nf, nattr); one wave per k-quarter --------
__global__ __launch_bounds__(256) void k_node_pre(
        const float* __restrict__ nf, const float* __restrict__ nattr,
        const float* __restrict__ l1w, float* __restrict__ xl) {
    int lane = threadIdx.x & 63;
    int q = threadIdx.x >> 6;              // wave-uniform 0..3
    int n = blockIdx.x * 64 + lane;
    if (n >= NN) return;

    float y[8];
    const float4* yp = (const float4*)(nattr + (long)n * 8);
    float4 y0 = yp[0], y1 = yp[1];
    y[0]=y0.x; y[1]=y0.y; y[2]=y0.z; y[3]=y0.w;
    y[4]=y1.x; y[5]=y1.y; y[6]=y1.z; y[7]=y1.w;
    float x[32];
    const float4* xp = (const float4*)(nf + (long)n * 32);
#pragma unroll
    for (int g = 0; g < 8; g++) {
        float4 t = xp[g];
        x[4*g]=t.x; x[4*g+1]=t.y; x[4*g+2]=t.z; x[4*g+3]=t.w;
    }

    float acc[8];
#pragma unroll
    for (int k = 0; k < 8; k++) acc[k] = 0.f;
    for (int u = 0; u < 32; u++) {
        float xu = x[u];
#pragma unroll
        for (int v = 0; v < 8; v++) {
            float z = xu * y[v];
            const float* wr = l1w + (u * 8 + v) * 32 + q * 8;  // wave-uniform
#pragma unroll
            for (int k = 0; k < 8; k++) acc[k] = fmaf(z, wr[k], acc[k]);
        }
    }
    float4* op = (float4*)(xl + (long)n * 32 + q * 8);
    float4 o0, o1;
    o0.x=acc[0]*0.0625f; o0.y=acc[1]*0.0625f; o0.z=acc[2]*0.0625f; o0.w=acc[3]*0.0625f;
    o1.x=acc[4]*0.0625f; o1.y=acc[5]*0.0625f; o1.z=acc[6]*0.0625f; o1.w=acc[7]*0.0625f;
    op[0] = o0; op[1] = o1;
}

// -------------------------- edge compute (no atomics) -----------------------
__global__ __launch_bounds__(256) void k_edge_g(
        const float* __restrict__ esc, const int* __restrict__ srcp,
        const float* __restrict__ ea_in, float* ea_out,
        const float* __restrict__ xl,
        const float* __restrict__ f0t, const float* __restrict__ f1,
        const float* __restrict__ sew, unsigned short* __restrict__ ef_bf) {
    int e = blockIdx.x * 256 + threadIdx.x;
    if (e >= NE) return;

    float es[16];
    const float4* ep = (const float4*)(esc + (long)e * 16);
#pragma unroll
    for (int g = 0; g < 4; g++) {
        float4 qv = ep[g];
        es[4*g]=qv.x; es[4*g+1]=qv.y; es[4*g+2]=qv.z; es[4*g+3]=qv.w;
    }
    float4 eaq = ((const float4*)ea_in)[e];
    float ea[4] = {eaq.x, eaq.y, eaq.z, eaq.w};

    float t[32];
#pragma unroll
    for (int u = 0; u < 32; u++) t[u] = 0.f;
    for (int j = 0; j < 64; j++) {                  // wave-uniform weight rows
        const float* c0 = f0t + j * 16;
        float ha = 0.f;
#pragma unroll
        for (int i = 0; i < 16; i++) ha = fmaf(es[i], c0[i], ha);
        float h = __sinf(ha * 0.25f);
        const float* r = f1 + j * 128;
#pragma unroll
        for (int u = 0; u < 32; u++) {
            float s = fmaf(ea[0], r[4*u], fmaf(ea[1], r[4*u+1],
                      fmaf(ea[2], r[4*u+2], ea[3] * r[4*u+3])));
            t[u] = fmaf(h, s, t[u]);
        }
    }

    int s_ = srcp[e];
    float ef[32];
    const float4* xp = (const float4*)(xl + (long)s_ * 32);
#pragma unroll
    for (int g = 0; g < 8; g++) {
        float4 xq = xp[g];
        ef[4*g+0] = xq.x * t[4*g+0] * 0.0625f;  // 1/sqrt(64)*1/sqrt(4)
        ef[4*g+1] = xq.y * t[4*g+1] * 0.0625f;
        ef[4*g+2] = xq.z * t[4*g+2] * 0.0625f;
        ef[4*g+3] = xq.w * t[4*g+3] * 0.0625f;
    }
    // store ef row as bf16 (64 B, coalesced)
    uint4* efp = (uint4*)(ef_bf + (long)e * 32);
#pragma unroll
    for (int g = 0; g < 4; g++) {
        uint4 w;
        w.x = f2us(ef[8*g+0]) | (f2us(ef[8*g+1]) << 16);
        w.y = f2us(ef[8*g+2]) | (f2us(ef[8*g+3]) << 16);
        w.z = f2us(ef[8*g+4]) | (f2us(ef[8*g+5]) << 16);
        w.w = f2us(ef[8*g+6]) | (f2us(ef[8*g+7]) << 16);
        efp[g] = w;
    }

    float eo[4] = {0.f, 0.f, 0.f, 0.f};
#pragma unroll
    for (int u = 0; u < 32; u++) {
        float efu = ef[u];
#pragma unroll
        for (int v = 0; v < 4; v++) {
            float p = efu * ea[v];
            const float* sw = sew + (u * 4 + v) * 4;
#pragma unroll
            for (int k = 0; k < 4; k++) eo[k] = fmaf(p, sw[k], eo[k]);
        }
    }
    constexpr float SCE_SCALE = 0.02209708691f;  // 1/sqrt(128)*1/sqrt(16)
    float4 o;
    o.x = ea[0] + eo[0]*SCE_SCALE; o.y = ea[1] + eo[1]*SCE_SCALE;
    o.z = ea[2] + eo[2]*SCE_SCALE; o.w = ea[3] + eo[3]*SCE_SCALE;
    ((float4*)ea_out)[e] = o;
}

// ---------------- fallback edge kernel (atomics), round-5 proven ------------
__global__ __launch_bounds__(256) void k_edge_a(
        const float* __restrict__ esc, const int* __restrict__ srcp,
        const int* __restrict__ dstp, const float* __restrict__ ea_in,
        float* ea_out, const float* __restrict__ xl,
        const float* __restrict__ f0t, const float* __restrict__ f1,
        const float* __restrict__ sew, float* __restrict__ agg) {
    int e = blockIdx.x * 256 + threadIdx.x;
    if (e >= NE) return;
    float es[16];
    const float4* ep = (const float4*)(esc + (long)e * 16);
#pragma unroll
    for (int g = 0; g < 4; g++) {
        float4 qv = ep[g];
        es[4*g]=qv.x; es[4*g+1]=qv.y; es[4*g+2]=qv.z; es[4*g+3]=qv.w;
    }
    float4 eaq = ((const float4*)ea_in)[e];
    float ea[4] = {eaq.x, eaq.y, eaq.z, eaq.w};
    float t[32];
#pragma unroll
    for (int u = 0; u < 32; u++) t[u] = 0.f;
    for (int j = 0; j < 64; j++) {
        const float* c0 = f0t + j * 16;
        float ha = 0.f;
#pragma unroll
        for (int i = 0; i < 16; i++) ha = fmaf(es[i], c0[i], ha);
        float h = __sinf(ha * 0.25f);
        const float* r = f1 + j * 128;
#pragma unroll
        for (int u = 0; u < 32; u++) {
            float s = fmaf(ea[0], r[4*u], fmaf(ea[1], r[4*u+1],
                      fmaf(ea[2], r[4*u+2], ea[3] * r[4*u+3])));
            t[u] = fmaf(h, s, t[u]);
        }
    }
    int s_ = srcp[e], d_ = dstp[e];
    float ef[32];
    const float4* xp = (const float4*)(xl + (long)s_ * 32);
#pragma unroll
    for (int g = 0; g < 8; g++) {
        float4 xq = xp[g];
        ef[4*g+0]=xq.x*t[4*g+0]*0.0625f; ef[4*g+1]=xq.y*t[4*g+1]*0.0625f;
        ef[4*g+2]=xq.z*t[4*g+2]*0.0625f; ef[4*g+3]=xq.w*t[4*g+3]*0.0625f;
    }
#pragma unroll
    for (int u = 0; u < 32; u++)
        atomicAdd(&agg[(long)d_ * 32 + u], ef[u] * 0.25f);
    float eo[4] = {0.f,0.f,0.f,0.f};
#pragma unroll
    for (int u = 0; u < 32; u++) {
        float efu = ef[u];
#pragma unroll
        for (int v = 0; v < 4; v++) {
            float p = efu * ea[v];
            const float* sw = sew + (u*4+v)*4;
#pragma unroll
            for (int k = 0; k < 4; k++) eo[k] = fmaf(p, sw[k], eo[k]);
        }
    }
    constexpr float SCE_SCALE = 0.02209708691f;
    float4 o;
    o.x=ea[0]+eo[0]*SCE_SCALE; o.y=ea[1]+eo[1]*SCE_SCALE;
    o.z=ea[2]+eo[2]*SCE_SCALE; o.w=ea[3]+eo[3]*SCE_SCALE;
    ((float4*)ea_out)[e] = o;
}

// -------------------------- gather (CSR) ------------------------------------
__global__ __launch_bounds__(256) void k_gather(
        const int* __restrict__ off, const int* __restrict__ eid,
        const unsigned short* __restrict__ ef, float* __restrict__ agg) {
    int lane = threadIdx.x & 31;
    int n = blockIdx.x * 8 + (threadIdx.x >> 5);
    if (n >= NN) return;
    int b = off[n], e = off[n + 1];
    float v = 0.f;
    for (int r = b; r < e; r++) {
        int id = eid[r];                               // broadcast load
        v += us2f(ef[(long)id * 32 + lane]);           // 64 B/row, coalesced
    }
    agg[(long)n * 32 + lane] = v * 0.25f;              // 1/sqrt(16)
}

// ------------- node post: sc + lin2 + alpha; one wave per k-quarter ---------
__global__ __launch_bounds__(256) void k_node_post(
        const float* __restrict__ nf_cur, const float* __restrict__ nattr,
        const float* __restrict__ scw, const float* __restrict__ l2w,
        const float* __restrict__ aw, const float* __restrict__ agg,
        float* __restrict__ nf_next, float* __restrict__ out_nf, int last) {
    int lane = threadIdx.x & 63;
    int q = threadIdx.x >> 6;              // wave-uniform
    int n = blockIdx.x * 64 + lane;
    if (n >= NN) return;

    float y[8];
    const float4* yp = (const float4*)(nattr + (long)n * 8);
    float4 y0 = yp[0], y1 = yp[1];
    y[0]=y0.x; y[1]=y0.y; y[2]=y0.z; y[3]=y0.w;
    y[4]=y1.x; y[5]=y1.y; y[6]=y1.z; y[7]=y1.w;

    float x[32], a[32];
    const float4* xp = (const float4*)(nf_cur + (long)n * 32);
    const float4* ap = (const float4*)(agg + (long)n * 32);
#pragma unroll
    for (int g = 0; g < 8; g++) {
        float4 t = xp[g];
        x[4*g]=t.x; x[4*g+1]=t.y; x[4*g+2]=t.z; x[4*g+3]=t.w;
        float4 s = ap[g];
        a[4*g]=s.x; a[4*g+1]=s.y; a[4*g+2]=s.z; a[4*g+3]=s.w;
    }

    float asc[8], a2[8], aA = 0.f;
#pragma unroll
    for (int k = 0; k < 8; k++) { asc[k] = 0.f; a2[k] = 0.f; }
    for (int u = 0; u < 32; u++) {
        float xu = x[u], au = a[u];
#pragma unroll
        for (int v = 0; v < 8; v++) {
            float zx = xu * y[v], za = au * y[v];
            const float* wa = scw + (u * 8 + v) * 32 + q * 8;
            const float* wb = l2w + (u * 8 + v) * 32 + q * 8;
#pragma unroll
            for (int k = 0; k < 8; k++) {
                asc[k] = fmaf(zx, wa[k], asc[k]);
                a2[k]  = fmaf(za, wb[k], a2[k]);
            }
            aA = fmaf(za, aw[u * 8 + v], aA);
        }
    }
    float alpha = aA * 0.0625f;
    long base = (long)n * 32 + q * 8;
    if (last) {
#pragma unroll
        for (int k = 0; k < 8; k++)
            out_nf[base + k] = asc[k] * 0.0625f + alpha * (a2[k] * 0.0625f);
    } else {
#pragma unroll
        for (int k = 0; k < 8; k++)
            nf_next[base + k] = __sinf(asc[k] * 0.0625f + alpha * (a2[k] * 0.0625f));
    }
}

// ---------------------------------------------------------------------------
extern "C" void kernel_launch(void* const* d_in, const int* in_sizes, int n_in,
                              void* d_out, int out_size, void* d_ws, size_t ws_size,
                              hipStream_t stream) {
    int I_nf, I_na, I_esrc, I_edst, I_ea, I_esc, I_sc, I_l1, I_l2, I_al, I_se, I_f0, I_f1;
    if (in_sizes[0] == 1600000) {            // dict order
        I_nf=0; I_na=1; I_esrc=2; I_edst=3; I_ea=4; I_esc=5;
        I_sc=6; I_l1=7; I_l2=8; I_al=9; I_se=10; I_f0=11; I_f1=12;
    } else {                                  // sorted keys
        I_al=0; I_ea=1; I_edst=2; I_esc=3; I_esrc=4; I_f0=5; I_f1=6;
        I_l1=7; I_l2=8; I_na=9; I_nf=10; I_sc=11; I_se=12;
    }
    const float* nf_in = (const float*)d_in[I_nf];
    const float* na    = (const float*)d_in[I_na];
    const int*   esrc  = (const int*)d_in[I_esrc];
    const int*   edst  = (const int*)d_in[I_edst];
    const float* ea_in = (const float*)d_in[I_ea];
    const float* escl  = (const float*)d_in[I_esc];
    const float* w_sc  = (const float*)d_in[I_sc];
    const float* w_l1  = (const float*)d_in[I_l1];
    const float* w_l2  = (const float*)d_in[I_l2];
    const float* w_al  = (const float*)d_in[I_al];
    const float* w_se  = (const float*)d_in[I_se];
    const float* w_f0  = (const float*)d_in[I_f0];
    const float* w_f1  = (const float*)d_in[I_f1];

    float* ws = (float*)d_ws;
    float* out_nf = (float*)d_out;              // f32 [50000*32]
    float* out_ea = out_nf + (long)NN * 32;     // f32 [800000*4]

    int*            csr_off = (int*)(ws + OFF_OFF);
    int*            csr_cur = (int*)(ws + OFF_CUR);
    int*            csr_eid = (int*)(ws + OFF_EID);
    unsigned short* ef_bf   = (unsigned short*)(ws + OFF_EF);
    const bool big = (ws_size >= NEED_BYTES);

    k_f0t<<<8, 256, 0, stream>>>(w_f0, ws + OFF_F0T);

    if (big) {  // CSR build (once; edge_dst is layer-invariant)
        hipMemsetAsync(csr_cur, 0, NN * sizeof(int), stream);
        k_hist<<<3125, 256, 0, stream>>>(edst, csr_cur);
        k_scan<<<1, 1024, 0, stream>>>(csr_cur, csr_off, csr_cur);
        k_scatter<<<3125, 256, 0, stream>>>(edst, csr_cur, csr_eid);
    }

    for (int l = 0; l < 2; l++) {
        int last = (l == 1);
        const float* nf_cur = (l == 0) ? nf_in : (ws + OFF_NF);
        const float* ea_cur = (l == 0) ? ea_in : out_ea;

        k_node_pre<<<782, 256, 0, stream>>>(nf_cur, na, w_l1 + l * 8192,
                                            out_nf /*xl scratch*/);
        if (big) {
            k_edge_g<<<3125, 256, 0, stream>>>(escl, esrc, ea_cur, out_ea,
                                               out_nf, ws + OFF_F0T + l * 1024,
                                               w_f1 + l * 8192, w_se + l * 512,
                                               ef_bf);
            k_gather<<<6250, 256, 0, stream>>>(csr_off, csr_eid, ef_bf,
                                               ws + OFF_AGG);
        } else {
            hipMemsetAsync(ws + OFF_AGG, 0, NN * 32 * sizeof(float), stream);
            k_edge_a<<<3125, 256, 0, stream>>>(escl, esrc, edst, ea_cur, out_ea,
                                               out_nf, ws + OFF_F0T + l * 1024,
                                               w_f1 + l * 8192, w_se + l * 512,
                                               ws + OFF_AGG);
        }
        k_node_post<<<782, 256, 0, stream>>>(nf_cur, na, w_sc + l * 8192,
                                             w_l2 + l * 8192, w_al + l * 256,
                                             ws + OFF_AGG, ws + OFF_NF,
                                             out_nf, last);
    }
}

// Round 7
// 1190.804 us; speedup vs baseline: 2.8469x; 1.1160x over previous
//
#include <hip/hip_runtime.h>
#include <hip/hip_bf16.h>

// ---------------------------------------------------------------------------
// MessagePassing (e3nn scalar conv, 2 layers) on MI355X. Inputs f32, out f32.
// Round 7: edge FC as MFMA GEMM. Per 64-edge block: H=sin(ES@W0/4) via VALU
// -> LDS (bf16), M = H@W1 via mfma_f32_16x16x32_bf16 (W1 pre-packed into
// B-frag layout), M kept in LDS, per-edge epilogue (t = ea·M, ef = x*t,
// sce) fused. gather+node_post fused (k_gpost). CSR built once.
// Dispatches: prep,hist,scan,scatter + 2x(node_pre, edge_m, gpost) = 10.
// ---------------------------------------------------------------------------

namespace {
constexpr int NN = 50000;
constexpr int NE = 800000;

// ws layout (float indices)
constexpr long OFF_NF  = 0;          // f32 [1,600,000] inter-layer nf
constexpr long OFF_F0T = 1600000;    // f32 [2048]  fc_w0^T [2][64][16]
constexpr long OFF_W1P = 1602048;    // ushort[16384] = 8192 floats (B-frags)
constexpr long OFF_OFF = 1610240;    // int [50001] CSR offsets
constexpr long OFF_CUR = 1660244;    // int [50000] counters/cursors
constexpr long OFF_EID = 1710244;    // int [800000] CSR edge ids
constexpr long OFF_EF  = 2510244;    // ushort [25,600,000] ef rows bf16
}

typedef __attribute__((ext_vector_type(8))) short short8;
typedef __attribute__((ext_vector_type(4))) float f32x4;

__device__ __forceinline__ float us2f(unsigned int u) {
    unsigned int x = u << 16; float f;
    __builtin_memcpy(&f, &x, sizeof(f));
    return f;
}
__device__ __forceinline__ unsigned int f2us(float f) {
    __hip_bfloat16 h = __float2bfloat16(f);
    unsigned short s;
    __builtin_memcpy(&s, &h, sizeof(s));
    return (unsigned int)s;
}

// ---------------- prep: zero cur + f0t transpose + W1 repack ----------------
__global__ __launch_bounds__(256) void k_prep(
        const float* __restrict__ f0, const float* __restrict__ f1,
        float* __restrict__ f0t, unsigned short* __restrict__ w1p,
        int* __restrict__ cur) {
    int i = blockIdx.x * 256 + threadIdx.x;
    if (i < NN) cur[i] = 0;
    if (i < 2048) {                       // f0t: src [l][ii(16)][j(64)]
        int l = i >> 10, q = i & 1023;
        int ii = q >> 6, j = q & 63;
        f0t[l * 1024 + j * 16 + ii] = f0[i];
    }
    if (i < 16384) {                      // W1 -> B-fragment layout
        int l = i >> 13, r = i & 8191;
        int kb = r >> 12, nt = (r >> 9) & 7, lane = (r >> 3) & 63, j8 = r & 7;
        int k = kb * 32 + (lane >> 4) * 8 + j8;
        int n = nt * 16 + (lane & 15);
        w1p[i] = (unsigned short)f2us(f1[l * 8192 + k * 128 + n]);
    }
}

// -------------------------- CSR build ---------------------------------------
__global__ void k_hist(const int* __restrict__ dst, int* __restrict__ cnt) {
    int e = blockIdx.x * 256 + threadIdx.x;
    if (e < NE) atomicAdd(&cnt[dst[e]], 1);
}

__global__ void k_scan(const int* __restrict__ cnt, int* __restrict__ off,
                       int* __restrict__ cur) {
    __shared__ int part[1024];
    int t = threadIdx.x;
    constexpr int CH = 49;
    int base = t * CH, s = 0;
    for (int i = 0; i < CH; i++) { int g = base + i; if (g < NN) s += cnt[g]; }
    part[t] = s; __syncthreads();
    for (int d = 1; d < 1024; d <<= 1) {
        int v = (t >= d) ? part[t - d] : 0;
        __syncthreads();
        part[t] += v;
        __syncthreads();
    }
    int run = (t == 0) ? 0 : part[t - 1];
    for (int i = 0; i < CH; i++) {
        int g = base + i;
        if (g < NN) { int c = cnt[g]; off[g] = run; cur[g] = run; run += c; }
    }
    if (t == 1023) off[NN] = run;
}

__global__ void k_scatter(const int* __restrict__ dst, int* __restrict__ cur,
                          int* __restrict__ eid) {
    int e = blockIdx.x * 256 + threadIdx.x;
    if (e >= NE) return;
    int pos = atomicAdd(&cur[dst[e]], 1);
    eid[pos] = e;
}

// ------------- node pre: x = lin1(nf, nattr); one wave per k-quarter --------
__global__ __launch_bounds__(256) void k_node_pre(
        const float* __restrict__ nf, const float* __restrict__ nattr,
        const float* __restrict__ l1w, float* __restrict__ xl) {
    int lane = threadIdx.x & 63;
    int q = threadIdx.x >> 6;
    int n = blockIdx.x * 64 + lane;
    if (n >= NN) return;

    float y[8];
    const float4* yp = (const float4*)(nattr + (long)n * 8);
    float4 y0 = yp[0], y1 = yp[1];
    y[0]=y0.x; y[1]=y0.y; y[2]=y0.z; y[3]=y0.w;
    y[4]=y1.x; y[5]=y1.y; y[6]=y1.z; y[7]=y1.w;
    float x[32];
    const float4* xp = (const float4*)(nf + (long)n * 32);
#pragma unroll
    for (int g = 0; g < 8; g++) {
        float4 t = xp[g];
        x[4*g]=t.x; x[4*g+1]=t.y; x[4*g+2]=t.z; x[4*g+3]=t.w;
    }
    float acc[8];
#pragma unroll
    for (int k = 0; k < 8; k++) acc[k] = 0.f;
    for (int u = 0; u < 32; u++) {
        float xu = x[u];
#pragma unroll
        for (int v = 0; v < 8; v++) {
            float z = xu * y[v];
            const float* wr = l1w + (u * 8 + v) * 32 + q * 8;
#pragma unroll
            for (int k = 0; k < 8; k++) acc[k] = fmaf(z, wr[k], acc[k]);
        }
    }
    float4* op = (float4*)(xl + (long)n * 32 + q * 8);
    float4 o0, o1;
    o0.x=acc[0]*0.0625f; o0.y=acc[1]*0.0625f; o0.z=acc[2]*0.0625f; o0.w=acc[3]*0.0625f;
    o1.x=acc[4]*0.0625f; o1.y=acc[5]*0.0625f; o1.z=acc[6]*0.0625f; o1.w=acc[7]*0.0625f;
    op[0] = o0; op[1] = o1;
}

// ----------------- MFMA edge kernel: 64 edges per 256-thr block -------------
__global__ __launch_bounds__(256) void k_edge_m(
        const float* __restrict__ esc, const int* __restrict__ srcp,
        const float* __restrict__ ea_in, float* ea_out,
        const float* __restrict__ xl,
        const float* __restrict__ f0t, const unsigned short* __restrict__ w1p,
        const float* __restrict__ sew, unsigned short* __restrict__ ef_bf) {
    __shared__ unsigned short Hs[64 * 80];   // H rows, stride 80 (10240 B)
    __shared__ float Ms[64 * 132];           // M rows, stride 132 (33792 B)
    __shared__ float EO[4 * 64 * 4];         // sce partials (4096 B)

    const int t = threadIdx.x;
    const int blk = blockIdx.x;
    const long e0 = (long)blk * 64;

    // ---- phase A: H[e][j] = sin(0.25 * es[e] . w0t[j]) -> LDS bf16 ----
    {
        int e = t & 63, jg = t >> 6;               // jg wave-uniform
        float es[16];
        const float4* ep = (const float4*)(esc + (e0 + e) * 16);
#pragma unroll
        for (int g = 0; g < 4; g++) {
            float4 q = ep[g];
            es[4*g]=q.x; es[4*g+1]=q.y; es[4*g+2]=q.z; es[4*g+3]=q.w;
        }
        unsigned int hw[8];
#pragma unroll
        for (int jj = 0; jj < 16; jj += 2) {
            const float* c0 = f0t + (jg * 16 + jj) * 16;
            const float* c1 = c0 + 16;
            float h0 = 0.f, h1 = 0.f;
#pragma unroll
            for (int i = 0; i < 16; i++) {
                h0 = fmaf(es[i], c0[i], h0);
                h1 = fmaf(es[i], c1[i], h1);
            }
            hw[jj >> 1] = f2us(__sinf(h0 * 0.25f)) | (f2us(__sinf(h1 * 0.25f)) << 16);
        }
        uint4* hp = (uint4*)(&Hs[e * 80 + jg * 16]);
        uint4 w0v; w0v.x=hw[0]; w0v.y=hw[1]; w0v.z=hw[2]; w0v.w=hw[3];
        uint4 w1v; w1v.x=hw[4]; w1v.y=hw[5]; w1v.z=hw[6]; w1v.w=hw[7];
        hp[0] = w0v; hp[1] = w1v;
    }
    __syncthreads();

    // ---- phase B: M = H @ W1 via MFMA; M/8 -> LDS f32 ----
    {
        int lane = t & 63, w = t >> 6;
        int m_base = w * 16;
        int mrow = m_base + (lane & 15);
        int quad = lane >> 4;
        const short8 a0 = *(const short8*)(&Hs[mrow * 80 + quad * 8]);
        const short8 a1 = *(const short8*)(&Hs[mrow * 80 + 32 + quad * 8]);
        f32x4 acc;
#pragma unroll
        for (int nt = 0; nt < 8; nt++) {
            const short8 b0 = *(const short8*)(w1p + ((0 * 8 + nt) * 64 + lane) * 8);
            const short8 b1 = *(const short8*)(w1p + ((1 * 8 + nt) * 64 + lane) * 8);
            acc[0]=0.f; acc[1]=0.f; acc[2]=0.f; acc[3]=0.f;
            acc = __builtin_amdgcn_mfma_f32_16x16x32_bf16(a0, b0, acc, 0, 0, 0);
            acc = __builtin_amdgcn_mfma_f32_16x16x32_bf16(a1, b1, acc, 0, 0, 0);
            int col = nt * 16 + (lane & 15);
#pragma unroll
            for (int r = 0; r < 4; r++) {
                int row = m_base + quad * 4 + r;
                Ms[row * 132 + col] = acc[r] * 0.125f;   // 1/sqrt(64)
            }
        }
    }
    __syncthreads();

    // ---- phase C: per-edge epilogue ----
    {
        int e = t & 63, p = t >> 6;                // p wave-uniform
        long ge = e0 + e;
        float4 eaq = ((const float4*)ea_in)[ge];
        float ea[4] = {eaq.x, eaq.y, eaq.z, eaq.w};
        int src = srcp[ge];
        float xv[8];
        const float4* xp = (const float4*)(xl + (long)src * 32 + p * 8);
        float4 x0 = xp[0], x1 = xp[1];
        xv[0]=x0.x; xv[1]=x0.y; xv[2]=x0.z; xv[3]=x0.w;
        xv[4]=x1.x; xv[5]=x1.y; xv[6]=x1.z; xv[7]=x1.w;

        float Mr[32];
        const float* mp = &Ms[e * 132 + p * 32];
#pragma unroll
        for (int g = 0; g < 8; g++) {
            float4 q = *(const float4*)(mp + 4 * g);
            Mr[4*g]=q.x; Mr[4*g+1]=q.y; Mr[4*g+2]=q.z; Mr[4*g+3]=q.w;
        }
        float eo[4] = {0.f, 0.f, 0.f, 0.f};
        unsigned int efw[4];
        float efbuf[8];
#pragma unroll
        for (int u = 0; u < 8; u++) {
            float tu = fmaf(ea[0], Mr[4*u], fmaf(ea[1], Mr[4*u+1],
                       fmaf(ea[2], Mr[4*u+2], ea[3] * Mr[4*u+3])));
            float ef = 0.5f * xv[u] * tu;          // 1/sqrt(4) from tp_uvu
            efbuf[u] = ef;
            const float* sw = sew + (p * 8 + u) * 16;
#pragma unroll
            for (int v = 0; v < 4; v++) {
                float pv = ef * ea[v];
#pragma unroll
                for (int k = 0; k < 4; k++) eo[k] = fmaf(pv, sw[v * 4 + k], eo[k]);
            }
        }
#pragma unroll
        for (int g = 0; g < 4; g++)
            efw[g] = f2us(efbuf[2*g]) | (f2us(efbuf[2*g+1]) << 16);
        // stage ef (reuse Hs region) + eo partials
        uint4* sp = (uint4*)(&Hs[e * 32 + p * 8]);
        uint4 wv; wv.x=efw[0]; wv.y=efw[1]; wv.z=efw[2]; wv.w=efw[3];
        sp[0] = wv;
        *(float4*)(&EO[(p * 64 + e) * 4]) = *(float4*)eo;
    }
    __syncthreads();

    // ---- phase D: coalesced stores ----
    {
        uint4 wv = ((const uint4*)Hs)[t];
        *(uint4*)(ef_bf + e0 * 32 + (long)t * 8) = wv;
    }
    if (t < 64) {
        long ge = e0 + t;
        float4 eaq = ((const float4*)ea_in)[ge];
        float4 s0 = *(float4*)(&EO[(0 * 64 + t) * 4]);
        float4 s1 = *(float4*)(&EO[(1 * 64 + t) * 4]);
        float4 s2 = *(float4*)(&EO[(2 * 64 + t) * 4]);
        float4 s3 = *(float4*)(&EO[(3 * 64 + t) * 4]);
        constexpr float SCE_SCALE = 0.02209708691f;   // 1/sqrt(128)/sqrt(16)
        float4 o;
        o.x = eaq.x + (s0.x + s1.x + s2.x + s3.x) * SCE_SCALE;
        o.y = eaq.y + (s0.y + s1.y + s2.y + s3.y) * SCE_SCALE;
        o.z = eaq.z + (s0.z + s1.z + s2.z + s3.z) * SCE_SCALE;
        o.w = eaq.w + (s0.w + s1.w + s2.w + s3.w) * SCE_SCALE;
        ((float4*)ea_out)[ge] = o;
    }
}

// --------- gather + node post fused: 64 nodes per 256-thr block -------------
__global__ __launch_bounds__(256) void k_gpost(
        const int* __restrict__ off, const int* __restrict__ eid,
        const unsigned short* __restrict__ ef,
        const float* __restrict__ nf_cur, const float* __restrict__ nattr,
        const float* __restrict__ scw, const float* __restrict__ l2w,
        const float* __restrict__ aw,
        float* __restrict__ nf_next, float* __restrict__ out_nf, int last) {
    __shared__ float As[64 * 36];
    const int t = threadIdx.x;

    // phase 1: gather agg rows (4 lanes per node, 8 u-slots each)
    {
        int nl = t >> 2, l4 = t & 3;
        int n = blockIdx.x * 64 + nl;
        float v[8] = {0.f,0.f,0.f,0.f,0.f,0.f,0.f,0.f};
        if (n < NN) {
            int b = off[n], en = off[n + 1];
            for (int r = b; r < en; r++) {
                int id = eid[r];
                uint4 q = *(const uint4*)(ef + (long)id * 32 + l4 * 8);
                v[0] += us2f(q.x & 0xFFFFu); v[1] += us2f(q.x >> 16);
                v[2] += us2f(q.y & 0xFFFFu); v[3] += us2f(q.y >> 16);
                v[4] += us2f(q.z & 0xFFFFu); v[5] += us2f(q.z >> 16);
                v[6] += us2f(q.w & 0xFFFFu); v[7] += us2f(q.w >> 16);
            }
        }
        float4 a0, a1;
        a0.x=v[0]*0.25f; a0.y=v[1]*0.25f; a0.z=v[2]*0.25f; a0.w=v[3]*0.25f;
        a1.x=v[4]*0.25f; a1.y=v[5]*0.25f; a1.z=v[6]*0.25f; a1.w=v[7]*0.25f;
        *(float4*)(&As[nl * 36 + l4 * 8])     = a0;
        *(float4*)(&As[nl * 36 + l4 * 8 + 4]) = a1;
    }
    __syncthreads();

    // phase 2: sc + lin2 + alpha (one wave per k-quarter)
    {
        int lane = t & 63, q = t >> 6;
        int n = blockIdx.x * 64 + lane;
        if (n >= NN) return;

        float y[8];
        const float4* yp = (const float4*)(nattr + (long)n * 8);
        float4 y0 = yp[0], y1 = yp[1];
        y[0]=y0.x; y[1]=y0.y; y[2]=y0.z; y[3]=y0.w;
        y[4]=y1.x; y[5]=y1.y; y[6]=y1.z; y[7]=y1.w;

        float x[32], a[32];
        const float4* xp = (const float4*)(nf_cur + (long)n * 32);
#pragma unroll
        for (int g = 0; g < 8; g++) {
            float4 tv = xp[g];
            x[4*g]=tv.x; x[4*g+1]=tv.y; x[4*g+2]=tv.z; x[4*g+3]=tv.w;
            float4 av = *(const float4*)(&As[lane * 36 + g * 4]);
            a[4*g]=av.x; a[4*g+1]=av.y; a[4*g+2]=av.z; a[4*g+3]=av.w;
        }

        float asc[8], a2[8], aA = 0.f;
#pragma unroll
        for (int k = 0; k < 8; k++) { asc[k] = 0.f; a2[k] = 0.f; }
        for (int u = 0; u < 32; u++) {
            float xu = x[u], au = a[u];
#pragma unroll
            for (int v = 0; v < 8; v++) {
                float zx = xu * y[v], za = au * y[v];
                const float* wa = scw + (u * 8 + v) * 32 + q * 8;
                const float* wb = l2w + (u * 8 + v) * 32 + q * 8;
#pragma unroll
                for (int k = 0; k < 8; k++) {
                    asc[k] = fmaf(zx, wa[k], asc[k]);
                    a2[k]  = fmaf(za, wb[k], a2[k]);
                }
                aA = fmaf(za, aw[u * 8 + v], aA);
            }
        }
        float alpha = aA * 0.0625f;
        long base = (long)n * 32 + q * 8;
        if (last) {
#pragma unroll
            for (int k = 0; k < 8; k++)
                out_nf[base + k] = asc[k] * 0.0625f + alpha * (a2[k] * 0.0625f);
        } else {
#pragma unroll
            for (int k = 0; k < 8; k++)
                nf_next[base + k] = __sinf(asc[k] * 0.0625f + alpha * (a2[k] * 0.0625f));
        }
    }
}

// ---------------------------------------------------------------------------
extern "C" void kernel_launch(void* const* d_in, const int* in_sizes, int n_in,
                              void* d_out, int out_size, void* d_ws, size_t ws_size,
                              hipStream_t stream) {
    int I_nf, I_na, I_esrc, I_edst, I_ea, I_esc, I_sc, I_l1, I_l2, I_al, I_se, I_f0, I_f1;
    if (in_sizes[0] == 1600000) {            // dict order
        I_nf=0; I_na=1; I_esrc=2; I_edst=3; I_ea=4; I_esc=5;
        I_sc=6; I_l1=7; I_l2=8; I_al=9; I_se=10; I_f0=11; I_f1=12;
    } else {                                  // sorted keys
        I_al=0; I_ea=1; I_edst=2; I_esc=3; I_esrc=4; I_f0=5; I_f1=6;
        I_l1=7; I_l2=8; I_na=9; I_nf=10; I_sc=11; I_se=12;
    }
    const float* nf_in = (const float*)d_in[I_nf];
    const float* na    = (const float*)d_in[I_na];
    const int*   esrc  = (const int*)d_in[I_esrc];
    const int*   edst  = (const int*)d_in[I_edst];
    const float* ea_in = (const float*)d_in[I_ea];
    const float* escl  = (const float*)d_in[I_esc];
    const float* w_sc  = (const float*)d_in[I_sc];
    const float* w_l1  = (const float*)d_in[I_l1];
    const float* w_l2  = (const float*)d_in[I_l2];
    const float* w_al  = (const float*)d_in[I_al];
    const float* w_se  = (const float*)d_in[I_se];
    const float* w_f0  = (const float*)d_in[I_f0];
    const float* w_f1  = (const float*)d_in[I_f1];

    float* ws = (float*)d_ws;
    float* out_nf = (float*)d_out;              // f32 [50000*32]
    float* out_ea = out_nf + (long)NN * 32;     // f32 [800000*4]

    float*          f0t     = ws + OFF_F0T;
    unsigned short* w1p     = (unsigned short*)(ws + OFF_W1P);
    int*            csr_off = (int*)(ws + OFF_OFF);
    int*            csr_cur = (int*)(ws + OFF_CUR);
    int*            csr_eid = (int*)(ws + OFF_EID);
    unsigned short* ef_bf   = (unsigned short*)(ws + OFF_EF);

    k_prep<<<196, 256, 0, stream>>>(w_f0, w_f1, f0t, w1p, csr_cur);
    k_hist<<<3125, 256, 0, stream>>>(edst, csr_cur);
    k_scan<<<1, 1024, 0, stream>>>(csr_cur, csr_off, csr_cur);
    k_scatter<<<3125, 256, 0, stream>>>(edst, csr_cur, csr_eid);

    for (int l = 0; l < 2; l++) {
        int last = (l == 1);
        const float* nf_cur = (l == 0) ? nf_in : (ws + OFF_NF);
        const float* ea_cur = (l == 0) ? ea_in : out_ea;

        k_node_pre<<<782, 256, 0, stream>>>(nf_cur, na, w_l1 + l * 8192,
                                            out_nf /*xl scratch*/);
        k_edge_m<<<12500, 256, 0, stream>>>(escl, esrc, ea_cur, out_ea,
                                            out_nf /*xl*/, f0t + l * 1024,
                                            w1p + l * 8192, w_se + l * 512,
                                            ef_bf);
        k_gpost<<<782, 256, 0, stream>>>(csr_off, csr_eid, ef_bf,
                                         nf_cur, na, w_sc + l * 8192,
                                         w_l2 + l * 8192, w_al + l * 256,
                                         ws + OFF_NF, out_nf, last);
    }
}

// Round 9
// 930.756 us; speedup vs baseline: 3.6423x; 1.2794x over previous
//
#include <hip/hip_runtime.h>
#include <hip/hip_bf16.h>

// ---------------------------------------------------------------------------
// MessagePassing (e3nn scalar conv, 2 layers) on MI355X. Inputs f32, out f32.
// Round 9: round-8 per-wave double-GEMM edge kernel + aliasing/barrier fix:
//   - may_alias types for all type-punned LDS traffic (TBAA reorder = r8 NaN)
//   - __syncthreads() at the two LDS phase boundaries (compiler mem barrier)
//   - T-tile stride 34 floats (conflict-free stores and reads)
// GEMM1: H = sin(ES @ 0.25*W0) (K=16 pad 32); GEMM2: T = G @ W2 with
// G[e,(j,v)] = H[e,j]*ea[e,v], K=256. ef rows stored at perm[e] -> gpost
// gather is fully contiguous.
// ---------------------------------------------------------------------------

namespace {
constexpr int NN = 50000;
constexpr int NE = 800000;

// ws layout (float indices)
constexpr long OFF_NF   = 0;         // f32 [1,600,000] inter-layer nf
constexpr long OFF_W0P  = 1600000;   // ushort[4096]  (2048 floats)
constexpr long OFF_W2P  = 1602048;   // ushort[16384] (8192 floats)
constexpr long OFF_OFF  = 1610240;   // int [50001] CSR offsets
constexpr long OFF_CUR  = 1660244;   // int [50000] cursors
constexpr long OFF_PERM = 1710244;   // int [800000] edge -> CSR slot
constexpr long OFF_EF   = 2510244;   // ushort [25,600,000] ef rows bf16
}

typedef __attribute__((ext_vector_type(8))) short short8;
typedef __attribute__((ext_vector_type(4))) float f32x4;
typedef unsigned int   __attribute__((may_alias)) u32a;
typedef unsigned short __attribute__((may_alias)) u16a;
typedef float          __attribute__((may_alias)) f32a;

__device__ __forceinline__ float us2f(unsigned int u) {
    unsigned int x = u << 16; float f;
    __builtin_memcpy(&f, &x, sizeof(f));
    return f;
}
__device__ __forceinline__ unsigned short f2us(float f) {
    __hip_bfloat16 h = __float2bfloat16(f);
    unsigned short s;
    __builtin_memcpy(&s, &h, sizeof(s));
    return s;
}

// ------------- hist + weight packing (cur must be zeroed before) ------------
__global__ __launch_bounds__(256) void k_hist(
        const int* __restrict__ dst, int* __restrict__ cnt,
        const float* __restrict__ f0, const float* __restrict__ f1,
        unsigned short* __restrict__ w0p, unsigned short* __restrict__ w2p) {
    int i = blockIdx.x * 256 + threadIdx.x;
    if (i < NE) atomicAdd(&cnt[dst[i]], 1);
    if (i < 4096) {                     // w0p [l][nt4][lane][i8], 0.25 folded
        int l = i >> 11, r = i & 2047;
        int nt = r >> 9, lane = (r >> 3) & 63, ii = r & 7;
        int k = (lane >> 4) * 8 + ii;           // K in [0,32), valid < 16
        int j = nt * 16 + (lane & 15);
        float v = (k < 16) ? 0.25f * f0[l * 1024 + k * 64 + j] : 0.f;
        w0p[i] = f2us(v);
    }
    if (i < 16384) {                    // w2p [l][kt*2+nt][lane][i8]
        int l = i >> 13, r = i & 8191;
        int g = r >> 9;                         // kt*2+nt
        int kt = g >> 1, nt = g & 1;
        int lane = (r >> 3) & 63, ii = r & 7;
        int K = kt * 32 + (lane >> 4) * 8 + ii; // K = j*4 + v
        int j = K >> 2, v = K & 3;
        int u = nt * 16 + (lane & 15);
        w2p[i] = f2us(f1[l * 8192 + j * 128 + u * 4 + v]);
    }
}

__global__ void k_scan(const int* __restrict__ cnt, int* __restrict__ off,
                       int* __restrict__ cur) {
    __shared__ int part[1024];
    int t = threadIdx.x;
    constexpr int CH = 49;
    int base = t * CH, s = 0;
    for (int i = 0; i < CH; i++) { int g = base + i; if (g < NN) s += cnt[g]; }
    part[t] = s; __syncthreads();
    for (int d = 1; d < 1024; d <<= 1) {
        int v = (t >= d) ? part[t - d] : 0;
        __syncthreads();
        part[t] += v;
        __syncthreads();
    }
    int run = (t == 0) ? 0 : part[t - 1];
    for (int i = 0; i < CH; i++) {
        int g = base + i;
        if (g < NN) { int c = cnt[g]; off[g] = run; cur[g] = run; run += c; }
    }
    if (t == 1023) off[NN] = run;
}

__global__ void k_perm(const int* __restrict__ dst, int* __restrict__ cur,
                       int* __restrict__ perm) {
    int e = blockIdx.x * 256 + threadIdx.x;
    if (e >= NE) return;
    perm[e] = atomicAdd(&cur[dst[e]], 1);
}

// ------------- node pre: x = lin1(nf, nattr); one wave per k-quarter --------
__global__ __launch_bounds__(256) void k_node_pre(
        const float* __restrict__ nf, const float* __restrict__ nattr,
        const float* __restrict__ l1w, float* __restrict__ xl) {
    int lane = threadIdx.x & 63;
    int q = threadIdx.x >> 6;
    int n = blockIdx.x * 64 + lane;
    if (n >= NN) return;

    float y[8];
    const float4* yp = (const float4*)(nattr + (long)n * 8);
    float4 y0 = yp[0], y1 = yp[1];
    y[0]=y0.x; y[1]=y0.y; y[2]=y0.z; y[3]=y0.w;
    y[4]=y1.x; y[5]=y1.y; y[6]=y1.z; y[7]=y1.w;
    float x[32];
    const float4* xp = (const float4*)(nf + (long)n * 32);
#pragma unroll
    for (int g = 0; g < 8; g++) {
        float4 t = xp[g];
        x[4*g]=t.x; x[4*g+1]=t.y; x[4*g+2]=t.z; x[4*g+3]=t.w;
    }
    float acc[8];
#pragma unroll
    for (int k = 0; k < 8; k++) acc[k] = 0.f;
    for (int u = 0; u < 32; u++) {
        float xu = x[u];
#pragma unroll
        for (int v = 0; v < 8; v++) {
            float z = xu * y[v];
            const float* wr = l1w + (u * 8 + v) * 32 + q * 8;
#pragma unroll
            for (int k = 0; k < 8; k++) acc[k] = fmaf(z, wr[k], acc[k]);
        }
    }
    float4* op = (float4*)(xl + (long)n * 32 + q * 8);
    float4 o0, o1;
    o0.x=acc[0]*0.0625f; o0.y=acc[1]*0.0625f; o0.z=acc[2]*0.0625f; o0.w=acc[3]*0.0625f;
    o1.x=acc[4]*0.0625f; o1.y=acc[5]*0.0625f; o1.z=acc[6]*0.0625f; o1.w=acc[7]*0.0625f;
    op[0] = o0; op[1] = o1;
}

// ------------- per-wave edge kernel: 64 edges/wave, 256 edges/block ---------
__global__ __launch_bounds__(256) void k_edge_w(
        const float* __restrict__ esc, const int* __restrict__ srcp,
        const int* __restrict__ perm, const float* __restrict__ ea_in,
        float* __restrict__ ea_out, const float* __restrict__ xl,
        const unsigned short* __restrict__ w0p,
        const unsigned short* __restrict__ w2p,
        const float* __restrict__ sew, unsigned short* __restrict__ ef_bf) {
    // per-wave scratch: H bf16 [64][stride 68] (8704 B) then T f32 [64][34]
    __shared__ __align__(16) unsigned char SCR[4][8704];

    const int t = threadIdx.x;
    const int w = t >> 6, lane = t & 63;
    const int l15 = lane & 15, quad = lane >> 4;
    const long e0 = ((long)blockIdx.x * 4 + w) * 64;
    u16a* Hs = (u16a*)SCR[w];
    f32a* Ts = (f32a*)SCR[w];

    // ---- GEMM1: H = sin(ES @ 0.25*W0) ; A zero-padded K=32 ----
    short8 bw0[4];
#pragma unroll
    for (int nt = 0; nt < 4; nt++)
        bw0[nt] = *(const short8*)(w0p + (nt * 64 + lane) * 8);
#pragma unroll
    for (int mt = 0; mt < 4; mt++) {
        int row = mt * 16 + l15;
        short8 a;
#pragma unroll
        for (int i = 0; i < 8; i++) a[i] = 0;
        if (quad < 2) {
            const float4* ep = (const float4*)(esc + (e0 + row) * 16 + quad * 8);
            float4 p0 = ep[0], p1 = ep[1];
            a[0]=(short)f2us(p0.x); a[1]=(short)f2us(p0.y);
            a[2]=(short)f2us(p0.z); a[3]=(short)f2us(p0.w);
            a[4]=(short)f2us(p1.x); a[5]=(short)f2us(p1.y);
            a[6]=(short)f2us(p1.z); a[7]=(short)f2us(p1.w);
        }
#pragma unroll
        for (int nt = 0; nt < 4; nt++) {
            f32x4 c; c[0]=0.f; c[1]=0.f; c[2]=0.f; c[3]=0.f;
            c = __builtin_amdgcn_mfma_f32_16x16x32_bf16(a, bw0[nt], c, 0, 0, 0);
#pragma unroll
            for (int r = 0; r < 4; r++) {
                int edge = mt * 16 + quad * 4 + r;      // C: row=quad*4+reg
                int j = nt * 16 + l15;                  // C: col=lane&15
                Hs[edge * 68 + j] = f2us(__sinf(c[r]));
            }
        }
    }
    __syncthreads();   // H visible + compiler memory barrier (TBAA-safe)

    // ---- GEMM2: T = G @ W2, G[e,(j,v)] = H[e,j]*ea[e,v], K=256 ----
    f32x4 acc[4][2];
#pragma unroll
    for (int mt = 0; mt < 4; mt++)
#pragma unroll
        for (int nt = 0; nt < 2; nt++) {
            acc[mt][nt][0]=0.f; acc[mt][nt][1]=0.f;
            acc[mt][nt][2]=0.f; acc[mt][nt][3]=0.f;
        }
#pragma unroll
    for (int mt = 0; mt < 4; mt++) {
        int row = mt * 16 + l15;
        float4 eaq = ((const float4*)ea_in)[e0 + row];
#pragma unroll
        for (int kt = 0; kt < 8; kt++) {
            // A-frag K range: kt*32 + quad*8 + i ; K=4j+v
            unsigned int hp = *(const u32a*)(Hs + row * 68 + kt * 8 + quad * 2);
            float H0 = us2f(hp & 0xFFFFu), H1 = us2f(hp >> 16);
            short8 a;
            a[0]=(short)f2us(H0*eaq.x); a[1]=(short)f2us(H0*eaq.y);
            a[2]=(short)f2us(H0*eaq.z); a[3]=(short)f2us(H0*eaq.w);
            a[4]=(short)f2us(H1*eaq.x); a[5]=(short)f2us(H1*eaq.y);
            a[6]=(short)f2us(H1*eaq.z); a[7]=(short)f2us(H1*eaq.w);
            const short8 b0 = *(const short8*)(w2p + ((kt*2+0)*64 + lane) * 8);
            const short8 b1 = *(const short8*)(w2p + ((kt*2+1)*64 + lane) * 8);
            acc[mt][0] = __builtin_amdgcn_mfma_f32_16x16x32_bf16(a, b0, acc[mt][0], 0, 0, 0);
            acc[mt][1] = __builtin_amdgcn_mfma_f32_16x16x32_bf16(a, b1, acc[mt][1], 0, 0, 0);
        }
    }
    __syncthreads();   // all H reads done before T overwrites the region
#pragma unroll
    for (int mt = 0; mt < 4; mt++)
#pragma unroll
        for (int nt = 0; nt < 2; nt++)
#pragma unroll
            for (int r = 0; r < 4; r++)
                Ts[(mt*16 + quad*4 + r) * 34 + nt*16 + l15] = acc[mt][nt][r] * 0.125f;

    // ---- epilogue: lane = edge (same-wave T dep; f32a both sides) ----
    {
        long ge = e0 + lane;
        float tv[32];
#pragma unroll
        for (int u = 0; u < 32; u++) tv[u] = Ts[lane * 34 + u];
        int src = srcp[ge], pm = perm[ge];
        float4 eaq = ((const float4*)ea_in)[ge];
        float ea[4] = {eaq.x, eaq.y, eaq.z, eaq.w};
        const float4* xp = (const float4*)(xl + (long)src * 32);
        float ef[32];
#pragma unroll
        for (int g = 0; g < 8; g++) {
            float4 xq = xp[g];
            ef[4*g+0] = 0.5f * xq.x * tv[4*g+0];   // 1/sqrt(4) from tp_uvu
            ef[4*g+1] = 0.5f * xq.y * tv[4*g+1];
            ef[4*g+2] = 0.5f * xq.z * tv[4*g+2];
            ef[4*g+3] = 0.5f * xq.w * tv[4*g+3];
        }
        uint4* efp = (uint4*)(ef_bf + (long)pm * 32);
#pragma unroll
        for (int g = 0; g < 4; g++) {
            uint4 wv;
            wv.x = (unsigned)f2us(ef[8*g+0]) | ((unsigned)f2us(ef[8*g+1]) << 16);
            wv.y = (unsigned)f2us(ef[8*g+2]) | ((unsigned)f2us(ef[8*g+3]) << 16);
            wv.z = (unsigned)f2us(ef[8*g+4]) | ((unsigned)f2us(ef[8*g+5]) << 16);
            wv.w = (unsigned)f2us(ef[8*g+6]) | ((unsigned)f2us(ef[8*g+7]) << 16);
            efp[g] = wv;
        }
        float eo[4] = {0.f, 0.f, 0.f, 0.f};
#pragma unroll
        for (int u = 0; u < 32; u++) {
            float efu = ef[u];
#pragma unroll
            for (int v = 0; v < 4; v++) {
                float p = efu * ea[v];
                const float* sw = sew + (u * 4 + v) * 4;
#pragma unroll
                for (int k = 0; k < 4; k++) eo[k] = fmaf(p, sw[k], eo[k]);
            }
        }
        constexpr float SCE_SCALE = 0.02209708691f;  // 1/sqrt(128)/sqrt(16)
        float4 o;
        o.x = ea[0] + eo[0]*SCE_SCALE; o.y = ea[1] + eo[1]*SCE_SCALE;
        o.z = ea[2] + eo[2]*SCE_SCALE; o.w = ea[3] + eo[3]*SCE_SCALE;
        ((float4*)ea_out)[ge] = o;
    }
}

// --------- gather (contiguous CSR rows) + node post fused -------------------
__global__ __launch_bounds__(256) void k_gpost(
        const int* __restrict__ off, const unsigned short* __restrict__ ef,
        const float* __restrict__ nf_cur, const float* __restrict__ nattr,
        const float* __restrict__ scw, const float* __restrict__ l2w,
        const float* __restrict__ aw,
        float* __restrict__ nf_next, float* __restrict__ out_nf, int last) {
    __shared__ float As[64 * 33];
    const int t = threadIdx.x;

    {   // phase 1: stream rows off[n]..off[n+1] (contiguous by construction)
        int nl = t >> 2, l4 = t & 3;
        int n = blockIdx.x * 64 + nl;
        float v[8] = {0.f,0.f,0.f,0.f,0.f,0.f,0.f,0.f};
        if (n < NN) {
            int b = off[n], en = off[n + 1];
            for (int r = b; r < en; r++) {
                uint4 q = *(const uint4*)(ef + (long)r * 32 + l4 * 8);
                v[0] += us2f(q.x & 0xFFFFu); v[1] += us2f(q.x >> 16);
                v[2] += us2f(q.y & 0xFFFFu); v[3] += us2f(q.y >> 16);
                v[4] += us2f(q.z & 0xFFFFu); v[5] += us2f(q.z >> 16);
                v[6] += us2f(q.w & 0xFFFFu); v[7] += us2f(q.w >> 16);
            }
        }
#pragma unroll
        for (int i = 0; i < 8; i++) As[nl * 33 + l4 * 8 + i] = v[i] * 0.25f;
    }
    __syncthreads();

    {   // phase 2: sc + lin2 + alpha (one wave per k-quarter)
        int lane = t & 63, q = t >> 6;
        int n = blockIdx.x * 64 + lane;
        if (n >= NN) return;

        float y[8];
        const float4* yp = (const float4*)(nattr + (long)n * 8);
        float4 y0 = yp[0], y1 = yp[1];
        y[0]=y0.x; y[1]=y0.y; y[2]=y0.z; y[3]=y0.w;
        y[4]=y1.x; y[5]=y1.y; y[6]=y1.z; y[7]=y1.w;

        float x[32], a[32];
        const float4* xp = (const float4*)(nf_cur + (long)n * 32);
#pragma unroll
        for (int g = 0; g < 8; g++) {
            float4 tv = xp[g];
            x[4*g]=tv.x; x[4*g+1]=tv.y; x[4*g+2]=tv.z; x[4*g+3]=tv.w;
        }
#pragma unroll
        for (int u = 0; u < 32; u++) a[u] = As[lane * 33 + u];

        float asc[8], a2[8], aA = 0.f;
#pragma unroll
        for (int k = 0; k < 8; k++) { asc[k] = 0.f; a2[k] = 0.f; }
        for (int u = 0; u < 32; u++) {
            float xu = x[u], au = a[u];
#pragma unroll
            for (int v = 0; v < 8; v++) {
                float zx = xu * y[v], za = au * y[v];
                const float* wa = scw + (u * 8 + v) * 32 + q * 8;
                const float* wb = l2w + (u * 8 + v) * 32 + q * 8;
#pragma unroll
                for (int k = 0; k < 8; k++) {
                    asc[k] = fmaf(zx, wa[k], asc[k]);
                    a2[k]  = fmaf(za, wb[k], a2[k]);
                }
                aA = fmaf(za, aw[u * 8 + v], aA);
            }
        }
        float alpha = aA * 0.0625f;
        long base = (long)n * 32 + q * 8;
        if (last) {
#pragma unroll
            for (int k = 0; k < 8; k++)
                out_nf[base + k] = asc[k] * 0.0625f + alpha * (a2[k] * 0.0625f);
        } else {
#pragma unroll
            for (int k = 0; k < 8; k++)
                nf_next[base + k] = __sinf(asc[k] * 0.0625f + alpha * (a2[k] * 0.0625f));
        }
    }
}

// ---------------------------------------------------------------------------
extern "C" void kernel_launch(void* const* d_in, const int* in_sizes, int n_in,
                              void* d_out, int out_size, void* d_ws, size_t ws_size,
                              hipStream_t stream) {
    int I_nf, I_na, I_esrc, I_edst, I_ea, I_esc, I_sc, I_l1, I_l2, I_al, I_se, I_f0, I_f1;
    if (in_sizes[0] == 1600000) {            // dict order
        I_nf=0; I_na=1; I_esrc=2; I_edst=3; I_ea=4; I_esc=5;
        I_sc=6; I_l1=7; I_l2=8; I_al=9; I_se=10; I_f0=11; I_f1=12;
    } else {                                  // sorted keys
        I_al=0; I_ea=1; I_edst=2; I_esc=3; I_esrc=4; I_f0=5; I_f1=6;
        I_l1=7; I_l2=8; I_na=9; I_nf=10; I_sc=11; I_se=12;
    }
    const float* nf_in = (const float*)d_in[I_nf];
    const float* na    = (const float*)d_in[I_na];
    const int*   esrc  = (const int*)d_in[I_esrc];
    const int*   edst  = (const int*)d_in[I_edst];
    const float* ea_in = (const float*)d_in[I_ea];
    const float* escl  = (const float*)d_in[I_esc];
    const float* w_sc  = (const float*)d_in[I_sc];
    const float* w_l1  = (const float*)d_in[I_l1];
    const float* w_l2  = (const float*)d_in[I_l2];
    const float* w_al  = (const float*)d_in[I_al];
    const float* w_se  = (const float*)d_in[I_se];
    const float* w_f0  = (const float*)d_in[I_f0];
    const float* w_f1  = (const float*)d_in[I_f1];

    float* ws = (float*)d_ws;
    float* out_nf = (float*)d_out;              // f32 [50000*32]
    float* out_ea = out_nf + (long)NN * 32;     // f32 [800000*4]

    unsigned short* w0p     = (unsigned short*)(ws + OFF_W0P);
    unsigned short* w2p     = (unsigned short*)(ws + OFF_W2P);
    int*            csr_off = (int*)(ws + OFF_OFF);
    int*            csr_cur = (int*)(ws + OFF_CUR);
    int*            perm    = (int*)(ws + OFF_PERM);
    unsigned short* ef_bf   = (unsigned short*)(ws + OFF_EF);

    hipMemsetAsync(csr_cur, 0, NN * sizeof(int), stream);
    k_hist<<<3125, 256, 0, stream>>>(edst, csr_cur, w_f0, w_f1, w0p, w2p);
    k_scan<<<1, 1024, 0, stream>>>(csr_cur, csr_off, csr_cur);
    k_perm<<<3125, 256, 0, stream>>>(edst, csr_cur, perm);

    for (int l = 0; l < 2; l++) {
        int last = (l == 1);
        const float* nf_cur = (l == 0) ? nf_in : (ws + OFF_NF);
        const float* ea_cur = (l == 0) ? ea_in : out_ea;

        k_node_pre<<<782, 256, 0, stream>>>(nf_cur, na, w_l1 + l * 8192,
                                            out_nf /*xl scratch*/);
        k_edge_w<<<3125, 256, 0, stream>>>(escl, esrc, perm, ea_cur, out_ea,
                                           out_nf /*xl*/, w0p + l * 2048,
                                           w2p + l * 8192, w_se + l * 512,
                                           ef_bf);
        k_gpost<<<782, 256, 0, stream>>>(csr_off, ef_bf,
                                         nf_cur, na, w_sc + l * 8192,
                                         w_l2 + l * 8192, w_al + l * 256,
                                         ws + OFF_NF, out_nf, last);
    }
}

// Round 10
// 523.614 us; speedup vs baseline: 6.4745x; 1.7776x over previous
//
#include <hip/hip_runtime.h>
#include <hip/hip_bf16.h>

// ---------------------------------------------------------------------------
// MessagePassing (e3nn scalar conv, 2 layers) on MI355X. Inputs f32, out f32.
// Round 10: node fctps as MFMA GEMMs (K=256=(u,v), same frag scheme as the
// proven edge kernel). npre: Z_nf@l1w. gpost: gather (8 lanes/node, shfl
// combine) + Z_nf@scw + Z_agg@[l2w|alpha] via MFMA, alpha via __shfl.
// Weight B-frags packed once in k_hist. Edge kernel/CSR unchanged from r9.
// ---------------------------------------------------------------------------

namespace {
constexpr int NN = 50000;
constexpr int NE = 800000;

// ws layout (float indices)
constexpr long OFF_NF   = 0;         // f32 [1,600,000] inter-layer nf
constexpr long OFF_W0P  = 1600000;   // ushort[4096]
constexpr long OFF_W2P  = 1602048;   // ushort[16384]
constexpr long OFF_WNP  = 1610240;   // ushort[57344] node-GEMM B-frags
constexpr long OFF_OFF  = 1638912;   // int [50001]
constexpr long OFF_CUR  = 1688913;   // int [50000]
constexpr long OFF_PERM = 1738913;   // int [800000]
constexpr long OFF_EF   = 2538916;   // ushort [25,600,000] (16-B aligned)
}

typedef __attribute__((ext_vector_type(8))) short short8;
typedef __attribute__((ext_vector_type(4))) float f32x4;
typedef unsigned int   __attribute__((may_alias)) u32a;
typedef unsigned short __attribute__((may_alias)) u16a;
typedef float          __attribute__((may_alias)) f32a;

__device__ __forceinline__ float us2f(unsigned int u) {
    unsigned int x = u << 16; float f;
    __builtin_memcpy(&f, &x, sizeof(f));
    return f;
}
__device__ __forceinline__ unsigned short f2us(float f) {
    __hip_bfloat16 h = __float2bfloat16(f);
    unsigned short s;
    __builtin_memcpy(&s, &h, sizeof(s));
    return s;
}

// ------------- hist + all weight packing ------------------------------------
__global__ __launch_bounds__(256) void k_hist(
        const int* __restrict__ dst, int* __restrict__ cnt,
        const float* __restrict__ f0, const float* __restrict__ f1,
        const float* __restrict__ l1w, const float* __restrict__ scw,
        const float* __restrict__ l2w, const float* __restrict__ aw,
        unsigned short* __restrict__ w0p, unsigned short* __restrict__ w2p,
        unsigned short* __restrict__ wnp) {
    int i = blockIdx.x * 256 + threadIdx.x;
    if (i < NE) atomicAdd(&cnt[dst[i]], 1);
    if (i < 4096) {                     // w0p [l][nt4][lane][i8], 0.25 folded
        int l = i >> 11, r = i & 2047;
        int nt = r >> 9, lane = (r >> 3) & 63, ii = r & 7;
        int k = (lane >> 4) * 8 + ii;
        int j = nt * 16 + (lane & 15);
        float v = (k < 16) ? 0.25f * f0[l * 1024 + k * 64 + j] : 0.f;
        w0p[i] = f2us(v);
    }
    if (i < 16384) {                    // w2p [l][kt*2+nt][lane][i8]
        int l = i >> 13, r = i & 8191;
        int g = r >> 9;
        int kt = g >> 1, nt = g & 1;
        int lane = (r >> 3) & 63, ii = r & 7;
        int K = kt * 32 + (lane >> 4) * 8 + ii;
        int j = K >> 2, v = K & 3;
        int u = nt * 16 + (lane & 15);
        w2p[i] = f2us(f1[l * 8192 + j * 128 + u * 4 + v]);
    }
    if (i < 57344) {                    // wnp [l][tile7][kt8][lane][i8]
        int l = i / 28672, r = i % 28672;
        int tile = r >> 12;
        int r2 = r & 4095;
        int kt = r2 >> 9, lane = (r2 >> 3) & 63, ii = r2 & 7;
        int k = kt * 32 + (lane >> 4) * 8 + ii;   // K = u*8+v
        int u = k >> 3, v = k & 7;
        int col = lane & 15;
        int uvb = l * 8192 + (u * 8 + v) * 32;
        float val;
        if (tile < 2)      val = l1w[uvb + tile * 16 + col];
        else if (tile < 4) val = scw[uvb + (tile - 2) * 16 + col];
        else if (tile < 6) val = l2w[uvb + (tile - 4) * 16 + col];
        else               val = (col == 0) ? aw[l * 256 + u * 8 + v] : 0.f;
        wnp[i] = f2us(val);
    }
}

__global__ void k_scan(const int* __restrict__ cnt, int* __restrict__ off,
                       int* __restrict__ cur) {
    __shared__ int part[1024];
    int t = threadIdx.x;
    constexpr int CH = 49;
    int base = t * CH, s = 0;
    for (int i = 0; i < CH; i++) { int g = base + i; if (g < NN) s += cnt[g]; }
    part[t] = s; __syncthreads();
    for (int d = 1; d < 1024; d <<= 1) {
        int v = (t >= d) ? part[t - d] : 0;
        __syncthreads();
        part[t] += v;
        __syncthreads();
    }
    int run = (t == 0) ? 0 : part[t - 1];
    for (int i = 0; i < CH; i++) {
        int g = base + i;
        if (g < NN) { int c = cnt[g]; off[g] = run; cur[g] = run; run += c; }
    }
    if (t == 1023) off[NN] = run;
}

__global__ void k_perm(const int* __restrict__ dst, int* __restrict__ cur,
                       int* __restrict__ perm) {
    int e = blockIdx.x * 256 + threadIdx.x;
    if (e >= NE) return;
    perm[e] = atomicAdd(&cur[dst[e]], 1);
}

// ---- staging helpers (nf/nattr tile -> LDS) --------------------------------
__device__ __forceinline__ void stage_xy(const float* __restrict__ nf,
                                         const float* __restrict__ nattr,
                                         long n0, int t, f32a* Xs, f32a* Ys) {
    {
        long e = n0 * 32 + t * 8;
        int n = t >> 2, u = (t & 3) * 8;
        f32a* d = &Xs[n * 33 + u];
        if (e + 8 <= (long)NN * 32) {
            const float4* p = (const float4*)(nf + e);
            float4 q0 = p[0], q1 = p[1];
            d[0]=q0.x; d[1]=q0.y; d[2]=q0.z; d[3]=q0.w;
            d[4]=q1.x; d[5]=q1.y; d[6]=q1.z; d[7]=q1.w;
        } else {
#pragma unroll
            for (int i = 0; i < 8; i++)
                d[i] = (e + i < (long)NN * 32) ? nf[e + i] : 0.f;
        }
    }
    if (t < 128) {
        long e = n0 * 8 + t * 4;
        int n = t >> 1, v = (t & 1) * 4;
        f32a* d = &Ys[n * 9 + v];
        if (e + 4 <= (long)NN * 8) {
            float4 q = *(const float4*)(nattr + e);
            d[0]=q.x; d[1]=q.y; d[2]=q.z; d[3]=q.w;
        } else {
#pragma unroll
            for (int i = 0; i < 4; i++)
                d[i] = (e + i < (long)NN * 8) ? nattr[e + i] : 0.f;
        }
    }
}

// ------------- node pre (MFMA): xl = lin1(nf, nattr) ------------------------
__global__ __launch_bounds__(256) void k_npre_m(
        const float* __restrict__ nf, const float* __restrict__ nattr,
        const unsigned short* __restrict__ wnp_l, float* __restrict__ xl) {
    __shared__ f32a Xs[64 * 33];
    __shared__ f32a Ys[64 * 9];
    const int t = threadIdx.x;
    const long n0 = (long)blockIdx.x * 64;
    stage_xy(nf, nattr, n0, t, Xs, Ys);
    __syncthreads();

    const int lane = t & 63, w = t >> 6;
    const int l15 = lane & 15, quad = lane >> 4;
    const int nb = w * 16;
    float y[8], xk[8];
#pragma unroll
    for (int v = 0; v < 8; v++) y[v] = Ys[(nb + l15) * 9 + v];
#pragma unroll
    for (int kt = 0; kt < 8; kt++) xk[kt] = Xs[(nb + l15) * 33 + kt * 4 + quad];

    f32x4 a0, a1;
    a0[0]=0.f;a0[1]=0.f;a0[2]=0.f;a0[3]=0.f;
    a1[0]=0.f;a1[1]=0.f;a1[2]=0.f;a1[3]=0.f;
#pragma unroll
    for (int kt = 0; kt < 8; kt++) {
        float xv = xk[kt];
        short8 a;
#pragma unroll
        for (int i = 0; i < 8; i++) a[i] = (short)f2us(xv * y[i]);
        const short8 b0 = *(const short8*)(wnp_l + ((0 * 8 + kt) * 512) + lane * 8);
        const short8 b1 = *(const short8*)(wnp_l + ((1 * 8 + kt) * 512) + lane * 8);
        a0 = __builtin_amdgcn_mfma_f32_16x16x32_bf16(a, b0, a0, 0, 0, 0);
        a1 = __builtin_amdgcn_mfma_f32_16x16x32_bf16(a, b1, a1, 0, 0, 0);
    }
#pragma unroll
    for (int r = 0; r < 4; r++) {
        long n = n0 + nb + quad * 4 + r;
        if (n < NN) {
            xl[n * 32 + l15]      = a0[r] * 0.0625f;
            xl[n * 32 + 16 + l15] = a1[r] * 0.0625f;
        }
    }
}

// ------------- per-wave edge kernel (unchanged from r9) ---------------------
__global__ __launch_bounds__(256) void k_edge_w(
        const float* __restrict__ esc, const int* __restrict__ srcp,
        const int* __restrict__ perm, const float* __restrict__ ea_in,
        float* __restrict__ ea_out, const float* __restrict__ xl,
        const unsigned short* __restrict__ w0p,
        const unsigned short* __restrict__ w2p,
        const float* __restrict__ sew, unsigned short* __restrict__ ef_bf) {
    __shared__ __align__(16) unsigned char SCR[4][8704];

    const int t = threadIdx.x;
    const int w = t >> 6, lane = t & 63;
    const int l15 = lane & 15, quad = lane >> 4;
    const long e0 = ((long)blockIdx.x * 4 + w) * 64;
    u16a* Hs = (u16a*)SCR[w];
    f32a* Ts = (f32a*)SCR[w];

    short8 bw0[4];
#pragma unroll
    for (int nt = 0; nt < 4; nt++)
        bw0[nt] = *(const short8*)(w0p + (nt * 64 + lane) * 8);
#pragma unroll
    for (int mt = 0; mt < 4; mt++) {
        int row = mt * 16 + l15;
        short8 a;
#pragma unroll
        for (int i = 0; i < 8; i++) a[i] = 0;
        if (quad < 2) {
            const float4* ep = (const float4*)(esc + (e0 + row) * 16 + quad * 8);
            float4 p0 = ep[0], p1 = ep[1];
            a[0]=(short)f2us(p0.x); a[1]=(short)f2us(p0.y);
            a[2]=(short)f2us(p0.z); a[3]=(short)f2us(p0.w);
            a[4]=(short)f2us(p1.x); a[5]=(short)f2us(p1.y);
            a[6]=(short)f2us(p1.z); a[7]=(short)f2us(p1.w);
        }
#pragma unroll
        for (int nt = 0; nt < 4; nt++) {
            f32x4 c; c[0]=0.f; c[1]=0.f; c[2]=0.f; c[3]=0.f;
            c = __builtin_amdgcn_mfma_f32_16x16x32_bf16(a, bw0[nt], c, 0, 0, 0);
#pragma unroll
            for (int r = 0; r < 4; r++) {
                int edge = mt * 16 + quad * 4 + r;
                int j = nt * 16 + l15;
                Hs[edge * 68 + j] = f2us(__sinf(c[r]));
            }
        }
    }
    __syncthreads();

    f32x4 acc[4][2];
#pragma unroll
    for (int mt = 0; mt < 4; mt++)
#pragma unroll
        for (int nt = 0; nt < 2; nt++) {
            acc[mt][nt][0]=0.f; acc[mt][nt][1]=0.f;
            acc[mt][nt][2]=0.f; acc[mt][nt][3]=0.f;
        }
#pragma unroll
    for (int mt = 0; mt < 4; mt++) {
        int row = mt * 16 + l15;
        float4 eaq = ((const float4*)ea_in)[e0 + row];
#pragma unroll
        for (int kt = 0; kt < 8; kt++) {
            unsigned int hp = *(const u32a*)(Hs + row * 68 + kt * 8 + quad * 2);
            float H0 = us2f(hp & 0xFFFFu), H1 = us2f(hp >> 16);
            short8 a;
            a[0]=(short)f2us(H0*eaq.x); a[1]=(short)f2us(H0*eaq.y);
            a[2]=(short)f2us(H0*eaq.z); a[3]=(short)f2us(H0*eaq.w);
            a[4]=(short)f2us(H1*eaq.x); a[5]=(short)f2us(H1*eaq.y);
            a[6]=(short)f2us(H1*eaq.z); a[7]=(short)f2us(H1*eaq.w);
            const short8 b0 = *(const short8*)(w2p + ((kt*2+0)*64 + lane) * 8);
            const short8 b1 = *(const short8*)(w2p + ((kt*2+1)*64 + lane) * 8);
            acc[mt][0] = __builtin_amdgcn_mfma_f32_16x16x32_bf16(a, b0, acc[mt][0], 0, 0, 0);
            acc[mt][1] = __builtin_amdgcn_mfma_f32_16x16x32_bf16(a, b1, acc[mt][1], 0, 0, 0);
        }
    }
    __syncthreads();
#pragma unroll
    for (int mt = 0; mt < 4; mt++)
#pragma unroll
        for (int nt = 0; nt < 2; nt++)
#pragma unroll
            for (int r = 0; r < 4; r++)
                Ts[(mt*16 + quad*4 + r) * 34 + nt*16 + l15] = acc[mt][nt][r] * 0.125f;

    {
        long ge = e0 + lane;
        float tv[32];
#pragma unroll
        for (int u = 0; u < 32; u++) tv[u] = Ts[lane * 34 + u];
        int src = srcp[ge], pm = perm[ge];
        float4 eaq = ((const float4*)ea_in)[ge];
        float ea[4] = {eaq.x, eaq.y, eaq.z, eaq.w};
        const float4* xp = (const float4*)(xl + (long)src * 32);
        float ef[32];
#pragma unroll
        for (int g = 0; g < 8; g++) {
            float4 xq = xp[g];
            ef[4*g+0] = 0.5f * xq.x * tv[4*g+0];
            ef[4*g+1] = 0.5f * xq.y * tv[4*g+1];
            ef[4*g+2] = 0.5f * xq.z * tv[4*g+2];
            ef[4*g+3] = 0.5f * xq.w * tv[4*g+3];
        }
        uint4* efp = (uint4*)(ef_bf + (long)pm * 32);
#pragma unroll
        for (int g = 0; g < 4; g++) {
            uint4 wv;
            wv.x = (unsigned)f2us(ef[8*g+0]) | ((unsigned)f2us(ef[8*g+1]) << 16);
            wv.y = (unsigned)f2us(ef[8*g+2]) | ((unsigned)f2us(ef[8*g+3]) << 16);
            wv.z = (unsigned)f2us(ef[8*g+4]) | ((unsigned)f2us(ef[8*g+5]) << 16);
            wv.w = (unsigned)f2us(ef[8*g+6]) | ((unsigned)f2us(ef[8*g+7]) << 16);
            efp[g] = wv;
        }
        float eo[4] = {0.f, 0.f, 0.f, 0.f};
#pragma unroll
        for (int u = 0; u < 32; u++) {
            float efu = ef[u];
#pragma unroll
            for (int v = 0; v < 4; v++) {
                float p = efu * ea[v];
                const float* sw = sew + (u * 4 + v) * 4;
#pragma unroll
                for (int k = 0; k < 4; k++) eo[k] = fmaf(p, sw[k], eo[k]);
            }
        }
        constexpr float SCE_SCALE = 0.02209708691f;
        float4 o;
        o.x = ea[0] + eo[0]*SCE_SCALE; o.y = ea[1] + eo[1]*SCE_SCALE;
        o.z = ea[2] + eo[2]*SCE_SCALE; o.w = ea[3] + eo[3]*SCE_SCALE;
        ((float4*)ea_out)[ge] = o;
    }
}

// --------- gather (8 lanes/node) + node post via MFMA -----------------------
__global__ __launch_bounds__(256) void k_gpost_m(
        const int* __restrict__ off, const unsigned short* __restrict__ ef,
        const float* __restrict__ nf_cur, const float* __restrict__ nattr,
        const unsigned short* __restrict__ wnp_l,
        float* __restrict__ nf_next, float* __restrict__ out_nf, int last) {
    __shared__ f32a Xs[64 * 33];
    __shared__ f32a As[64 * 33];
    __shared__ f32a Ys[64 * 9];
    const int t = threadIdx.x;
    const long n0 = (long)blockIdx.x * 64;
    stage_xy(nf_cur, nattr, n0, t, Xs, Ys);

    {   // gather: 8 lanes/node (even/odd rows), 2 node batches
        int slot = t >> 3, g = (t >> 2) & 1, l4 = t & 3;
#pragma unroll
        for (int batch = 0; batch < 2; batch++) {
            int nl = batch * 32 + slot;
            long n = n0 + nl;
            float v[8] = {0.f,0.f,0.f,0.f,0.f,0.f,0.f,0.f};
            if (n < NN) {
                int b = off[n] + g, en = off[n + 1];
                for (int r = b; r < en; r += 2) {
                    uint4 q = *(const uint4*)(ef + (long)r * 32 + l4 * 8);
                    v[0] += us2f(q.x & 0xFFFFu); v[1] += us2f(q.x >> 16);
                    v[2] += us2f(q.y & 0xFFFFu); v[3] += us2f(q.y >> 16);
                    v[4] += us2f(q.z & 0xFFFFu); v[5] += us2f(q.z >> 16);
                    v[6] += us2f(q.w & 0xFFFFu); v[7] += us2f(q.w >> 16);
                }
            }
#pragma unroll
            for (int i = 0; i < 8; i++) v[i] += __shfl_xor(v[i], 4);
            if (g == 0) {
#pragma unroll
                for (int i = 0; i < 8; i++)
                    As[nl * 33 + l4 * 8 + i] = v[i] * 0.25f;
            }
        }
    }
    __syncthreads();

    const int lane = t & 63, w = t >> 6;
    const int l15 = lane & 15, quad = lane >> 4;
    const int nb = w * 16;
    float y[8], xk[8], ak[8];
#pragma unroll
    for (int v = 0; v < 8; v++) y[v] = Ys[(nb + l15) * 9 + v];
#pragma unroll
    for (int kt = 0; kt < 8; kt++) {
        xk[kt] = Xs[(nb + l15) * 33 + kt * 4 + quad];
        ak[kt] = As[(nb + l15) * 33 + kt * 4 + quad];
    }
    f32x4 sc0, sc1, l20, l21, al;
    sc0[0]=0.f;sc0[1]=0.f;sc0[2]=0.f;sc0[3]=0.f;
    sc1 = sc0; l20 = sc0; l21 = sc0; al = sc0;
#pragma unroll
    for (int kt = 0; kt < 8; kt++) {
        float xv = xk[kt], av = ak[kt];
        short8 ax, ag;
#pragma unroll
        for (int i = 0; i < 8; i++) {
            ax[i] = (short)f2us(xv * y[i]);
            ag[i] = (short)f2us(av * y[i]);
        }
        const short8 b2 = *(const short8*)(wnp_l + ((2 * 8 + kt) * 512) + lane * 8);
        const short8 b3 = *(const short8*)(wnp_l + ((3 * 8 + kt) * 512) + lane * 8);
        const short8 b4 = *(const short8*)(wnp_l + ((4 * 8 + kt) * 512) + lane * 8);
        const short8 b5 = *(const short8*)(wnp_l + ((5 * 8 + kt) * 512) + lane * 8);
        const short8 b6 = *(const short8*)(wnp_l + ((6 * 8 + kt) * 512) + lane * 8);
        sc0 = __builtin_amdgcn_mfma_f32_16x16x32_bf16(ax, b2, sc0, 0, 0, 0);
        sc1 = __builtin_amdgcn_mfma_f32_16x16x32_bf16(ax, b3, sc1, 0, 0, 0);
        l20 = __builtin_amdgcn_mfma_f32_16x16x32_bf16(ag, b4, l20, 0, 0, 0);
        l21 = __builtin_amdgcn_mfma_f32_16x16x32_bf16(ag, b5, l21, 0, 0, 0);
        al  = __builtin_amdgcn_mfma_f32_16x16x32_bf16(ag, b6, al,  0, 0, 0);
    }
#pragma unroll
    for (int r = 0; r < 4; r++) {
        float alpha = __shfl(al[r], quad * 16) * 0.0625f;  // col 0 of alpha tile
        long n = n0 + nb + quad * 4 + r;
        if (n < NN) {
            float o0 = sc0[r] * 0.0625f + alpha * (l20[r] * 0.0625f);
            float o1 = sc1[r] * 0.0625f + alpha * (l21[r] * 0.0625f);
            if (last) {
                out_nf[n * 32 + l15]      = o0;
                out_nf[n * 32 + 16 + l15] = o1;
            } else {
                nf_next[n * 32 + l15]      = __sinf(o0);
                nf_next[n * 32 + 16 + l15] = __sinf(o1);
            }
        }
    }
}

// ---------------------------------------------------------------------------
extern "C" void kernel_launch(void* const* d_in, const int* in_sizes, int n_in,
                              void* d_out, int out_size, void* d_ws, size_t ws_size,
                              hipStream_t stream) {
    int I_nf, I_na, I_esrc, I_edst, I_ea, I_esc, I_sc, I_l1, I_l2, I_al, I_se, I_f0, I_f1;
    if (in_sizes[0] == 1600000) {            // dict order
        I_nf=0; I_na=1; I_esrc=2; I_edst=3; I_ea=4; I_esc=5;
        I_sc=6; I_l1=7; I_l2=8; I_al=9; I_se=10; I_f0=11; I_f1=12;
    } else {                                  // sorted keys
        I_al=0; I_ea=1; I_edst=2; I_esc=3; I_esrc=4; I_f0=5; I_f1=6;
        I_l1=7; I_l2=8; I_na=9; I_nf=10; I_sc=11; I_se=12;
    }
    const float* nf_in = (const float*)d_in[I_nf];
    const float* na    = (const float*)d_in[I_na];
    const int*   esrc  = (const int*)d_in[I_esrc];
    const int*   edst  = (const int*)d_in[I_edst];
    const float* ea_in = (const float*)d_in[I_ea];
    const float* escl  = (const float*)d_in[I_esc];
    const float* w_sc  = (const float*)d_in[I_sc];
    const float* w_l1  = (const float*)d_in[I_l1];
    const float* w_l2  = (const float*)d_in[I_l2];
    const float* w_al  = (const float*)d_in[I_al];
    const float* w_se  = (const float*)d_in[I_se];
    const float* w_f0  = (const float*)d_in[I_f0];
    const float* w_f1  = (const float*)d_in[I_f1];

    float* ws = (float*)d_ws;
    float* out_nf = (float*)d_out;              // f32 [50000*32]
    float* out_ea = out_nf + (long)NN * 32;     // f32 [800000*4]

    unsigned short* w0p     = (unsigned short*)(ws + OFF_W0P);
    unsigned short* w2p     = (unsigned short*)(ws + OFF_W2P);
    unsigned short* wnp     = (unsigned short*)(ws + OFF_WNP);
    int*            csr_off = (int*)(ws + OFF_OFF);
    int*            csr_cur = (int*)(ws + OFF_CUR);
    int*            perm    = (int*)(ws + OFF_PERM);
    unsigned short* ef_bf   = (unsigned short*)(ws + OFF_EF);

    hipMemsetAsync(csr_cur, 0, NN * sizeof(int), stream);
    k_hist<<<3125, 256, 0, stream>>>(edst, csr_cur, w_f0, w_f1,
                                     w_l1, w_sc, w_l2, w_al, w0p, w2p, wnp);
    k_scan<<<1, 1024, 0, stream>>>(csr_cur, csr_off, csr_cur);
    k_perm<<<3125, 256, 0, stream>>>(edst, csr_cur, perm);

    for (int l = 0; l < 2; l++) {
        int last = (l == 1);
        const float* nf_cur = (l == 0) ? nf_in : (ws + OFF_NF);
        const float* ea_cur = (l == 0) ? ea_in : out_ea;

        k_npre_m<<<782, 256, 0, stream>>>(nf_cur, na, wnp + l * 28672,
                                          out_nf /*xl scratch*/);
        k_edge_w<<<3125, 256, 0, stream>>>(escl, esrc, perm, ea_cur, out_ea,
                                           out_nf /*xl*/, w0p + l * 2048,
                                           w2p + l * 8192, w_se + l * 512,
                                           ef_bf);
        k_gpost_m<<<782, 256, 0, stream>>>(csr_off, ef_bf,
                                           nf_cur, na, wnp + l * 28672,
                                           ws + OFF_NF, out_nf, last);
    }
}

// Round 11
// 406.647 us; speedup vs baseline: 8.3368x; 1.2876x over previous
//
#include <hip/hip_runtime.h>
#include <hip/hip_bf16.h>

// ---------------------------------------------------------------------------
// MessagePassing (e3nn scalar conv, 2 layers) on MI355X. Inputs f32, out f32.
// Round 11: replace the 1-block scan (127 us, 0.15% occupancy) with a
// 3-phase parallel scan (block-reduce, scan-of-sums, block-scan+emit).
// Everything else unchanged from round 10 (proven).
// ---------------------------------------------------------------------------

namespace {
constexpr int NN = 50000;
constexpr int NE = 800000;
constexpr int SCAN_BLOCKS = 196;     // ceil(50000/256)

// ws layout (float indices)
constexpr long OFF_NF   = 0;         // f32 [1,600,000] inter-layer nf
constexpr long OFF_W0P  = 1600000;   // ushort[4096]
constexpr long OFF_W2P  = 1602048;   // ushort[16384]
constexpr long OFF_WNP  = 1610240;   // ushort[57344] node-GEMM B-frags
constexpr long OFF_OFF  = 1638912;   // int [50001]
constexpr long OFF_CUR  = 1688913;   // int [50000]
constexpr long OFF_PERM = 1738913;   // int [800000]
constexpr long OFF_BSUM = 2538913;   // int [256] block sums
constexpr long OFF_EF   = 2539172;   // ushort [25,600,000] (16-B aligned)
}

typedef __attribute__((ext_vector_type(8))) short short8;
typedef __attribute__((ext_vector_type(4))) float f32x4;
typedef unsigned int   __attribute__((may_alias)) u32a;
typedef unsigned short __attribute__((may_alias)) u16a;
typedef float          __attribute__((may_alias)) f32a;

__device__ __forceinline__ float us2f(unsigned int u) {
    unsigned int x = u << 16; float f;
    __builtin_memcpy(&f, &x, sizeof(f));
    return f;
}
__device__ __forceinline__ unsigned short f2us(float f) {
    __hip_bfloat16 h = __float2bfloat16(f);
    unsigned short s;
    __builtin_memcpy(&s, &h, sizeof(s));
    return s;
}

// ------------- hist + all weight packing ------------------------------------
__global__ __launch_bounds__(256) void k_hist(
        const int* __restrict__ dst, int* __restrict__ cnt,
        const float* __restrict__ f0, const float* __restrict__ f1,
        const float* __restrict__ l1w, const float* __restrict__ scw,
        const float* __restrict__ l2w, const float* __restrict__ aw,
        unsigned short* __restrict__ w0p, unsigned short* __restrict__ w2p,
        unsigned short* __restrict__ wnp) {
    int i = blockIdx.x * 256 + threadIdx.x;
    if (i < NE) atomicAdd(&cnt[dst[i]], 1);
    if (i < 4096) {                     // w0p [l][nt4][lane][i8], 0.25 folded
        int l = i >> 11, r = i & 2047;
        int nt = r >> 9, lane = (r >> 3) & 63, ii = r & 7;
        int k = (lane >> 4) * 8 + ii;
        int j = nt * 16 + (lane & 15);
        float v = (k < 16) ? 0.25f * f0[l * 1024 + k * 64 + j] : 0.f;
        w0p[i] = f2us(v);
    }
    if (i < 16384) {                    // w2p [l][kt*2+nt][lane][i8]
        int l = i >> 13, r = i & 8191;
        int g = r >> 9;
        int kt = g >> 1, nt = g & 1;
        int lane = (r >> 3) & 63, ii = r & 7;
        int K = kt * 32 + (lane >> 4) * 8 + ii;
        int j = K >> 2, v = K & 3;
        int u = nt * 16 + (lane & 15);
        w2p[i] = f2us(f1[l * 8192 + j * 128 + u * 4 + v]);
    }
    if (i < 57344) {                    // wnp [l][tile7][kt8][lane][i8]
        int l = i / 28672, r = i % 28672;
        int tile = r >> 12;
        int r2 = r & 4095;
        int kt = r2 >> 9, lane = (r2 >> 3) & 63, ii = r2 & 7;
        int k = kt * 32 + (lane >> 4) * 8 + ii;   // K = u*8+v
        int u = k >> 3, v = k & 7;
        int col = lane & 15;
        int uvb = l * 8192 + (u * 8 + v) * 32;
        float val;
        if (tile < 2)      val = l1w[uvb + tile * 16 + col];
        else if (tile < 4) val = scw[uvb + (tile - 2) * 16 + col];
        else if (tile < 6) val = l2w[uvb + (tile - 4) * 16 + col];
        else               val = (col == 0) ? aw[l * 256 + u * 8 + v] : 0.f;
        wnp[i] = f2us(val);
    }
}

// ------------------------- 3-phase parallel scan ----------------------------
__global__ __launch_bounds__(256) void k_scan1(const int* __restrict__ cnt,
                                               int* __restrict__ bsum) {
    __shared__ int s[256];
    int t = threadIdx.x;
    int i = blockIdx.x * 256 + t;
    s[t] = (i < NN) ? cnt[i] : 0;
    __syncthreads();
    for (int d = 128; d > 0; d >>= 1) {
        if (t < d) s[t] += s[t + d];
        __syncthreads();
    }
    if (t == 0) bsum[blockIdx.x] = s[0];
}

__global__ __launch_bounds__(256) void k_scan2(int* __restrict__ bsum) {
    __shared__ int s[256];
    int t = threadIdx.x;
    int v = (t < SCAN_BLOCKS) ? bsum[t] : 0;
    s[t] = v; __syncthreads();
    for (int d = 1; d < 256; d <<= 1) {
        int x = (t >= d) ? s[t - d] : 0;
        __syncthreads();
        s[t] += x;
        __syncthreads();
    }
    if (t < SCAN_BLOCKS) bsum[t] = s[t] - v;   // exclusive
}

__global__ __launch_bounds__(256) void k_scan3(
        const int* __restrict__ cnt, const int* __restrict__ bsum,
        int* __restrict__ off, int* __restrict__ cur) {
    __shared__ int s[256];
    int t = threadIdx.x;
    int i = blockIdx.x * 256 + t;
    int v = (i < NN) ? cnt[i] : 0;
    s[t] = v; __syncthreads();
    for (int d = 1; d < 256; d <<= 1) {
        int x = (t >= d) ? s[t - d] : 0;
        __syncthreads();
        s[t] += x;
        __syncthreads();
    }
    int excl = s[t] - v + bsum[blockIdx.x];
    if (i < NN) { off[i] = excl; cur[i] = excl; }
    if (i == NN - 1) off[NN] = excl + v;       // == NE
}

__global__ void k_perm(const int* __restrict__ dst, int* __restrict__ cur,
                       int* __restrict__ perm) {
    int e = blockIdx.x * 256 + threadIdx.x;
    if (e >= NE) return;
    perm[e] = atomicAdd(&cur[dst[e]], 1);
}

// ---- staging helpers (nf/nattr tile -> LDS) --------------------------------
__device__ __forceinline__ void stage_xy(const float* __restrict__ nf,
                                         const float* __restrict__ nattr,
                                         long n0, int t, f32a* Xs, f32a* Ys) {
    {
        long e = n0 * 32 + t * 8;
        int n = t >> 2, u = (t & 3) * 8;
        f32a* d = &Xs[n * 33 + u];
        if (e + 8 <= (long)NN * 32) {
            const float4* p = (const float4*)(nf + e);
            float4 q0 = p[0], q1 = p[1];
            d[0]=q0.x; d[1]=q0.y; d[2]=q0.z; d[3]=q0.w;
            d[4]=q1.x; d[5]=q1.y; d[6]=q1.z; d[7]=q1.w;
        } else {
#pragma unroll
            for (int i = 0; i < 8; i++)
                d[i] = (e + i < (long)NN * 32) ? nf[e + i] : 0.f;
        }
    }
    if (t < 128) {
        long e = n0 * 8 + t * 4;
        int n = t >> 1, v = (t & 1) * 4;
        f32a* d = &Ys[n * 9 + v];
        if (e + 4 <= (long)NN * 8) {
            float4 q = *(const float4*)(nattr + e);
            d[0]=q.x; d[1]=q.y; d[2]=q.z; d[3]=q.w;
        } else {
#pragma unroll
            for (int i = 0; i < 4; i++)
                d[i] = (e + i < (long)NN * 8) ? nattr[e + i] : 0.f;
        }
    }
}

// ------------- node pre (MFMA): xl = lin1(nf, nattr) ------------------------
__global__ __launch_bounds__(256) void k_npre_m(
        const float* __restrict__ nf, const float* __restrict__ nattr,
        const unsigned short* __restrict__ wnp_l, float* __restrict__ xl) {
    __shared__ f32a Xs[64 * 33];
    __shared__ f32a Ys[64 * 9];
    const int t = threadIdx.x;
    const long n0 = (long)blockIdx.x * 64;
    stage_xy(nf, nattr, n0, t, Xs, Ys);
    __syncthreads();

    const int lane = t & 63, w = t >> 6;
    const int l15 = lane & 15, quad = lane >> 4;
    const int nb = w * 16;
    float y[8], xk[8];
#pragma unroll
    for (int v = 0; v < 8; v++) y[v] = Ys[(nb + l15) * 9 + v];
#pragma unroll
    for (int kt = 0; kt < 8; kt++) xk[kt] = Xs[(nb + l15) * 33 + kt * 4 + quad];

    f32x4 a0, a1;
    a0[0]=0.f;a0[1]=0.f;a0[2]=0.f;a0[3]=0.f;
    a1[0]=0.f;a1[1]=0.f;a1[2]=0.f;a1[3]=0.f;
#pragma unroll
    for (int kt = 0; kt < 8; kt++) {
        float xv = xk[kt];
        short8 a;
#pragma unroll
        for (int i = 0; i < 8; i++) a[i] = (short)f2us(xv * y[i]);
        const short8 b0 = *(const short8*)(wnp_l + ((0 * 8 + kt) * 512) + lane * 8);
        const short8 b1 = *(const short8*)(wnp_l + ((1 * 8 + kt) * 512) + lane * 8);
        a0 = __builtin_amdgcn_mfma_f32_16x16x32_bf16(a, b0, a0, 0, 0, 0);
        a1 = __builtin_amdgcn_mfma_f32_16x16x32_bf16(a, b1, a1, 0, 0, 0);
    }
#pragma unroll
    for (int r = 0; r < 4; r++) {
        long n = n0 + nb + quad * 4 + r;
        if (n < NN) {
            xl[n * 32 + l15]      = a0[r] * 0.0625f;
            xl[n * 32 + 16 + l15] = a1[r] * 0.0625f;
        }
    }
}

// ------------- per-wave edge kernel (unchanged from r9) ---------------------
__global__ __launch_bounds__(256) void k_edge_w(
        const float* __restrict__ esc, const int* __restrict__ srcp,
        const int* __restrict__ perm, const float* __restrict__ ea_in,
        float* __restrict__ ea_out, const float* __restrict__ xl,
        const unsigned short* __restrict__ w0p,
        const unsigned short* __restrict__ w2p,
        const float* __restrict__ sew, unsigned short* __restrict__ ef_bf) {
    __shared__ __align__(16) unsigned char SCR[4][8704];

    const int t = threadIdx.x;
    const int w = t >> 6, lane = t & 63;
    const int l15 = lane & 15, quad = lane >> 4;
    const long e0 = ((long)blockIdx.x * 4 + w) * 64;
    u16a* Hs = (u16a*)SCR[w];
    f32a* Ts = (f32a*)SCR[w];

    short8 bw0[4];
#pragma unroll
    for (int nt = 0; nt < 4; nt++)
        bw0[nt] = *(const short8*)(w0p + (nt * 64 + lane) * 8);
#pragma unroll
    for (int mt = 0; mt < 4; mt++) {
        int row = mt * 16 + l15;
        short8 a;
#pragma unroll
        for (int i = 0; i < 8; i++) a[i] = 0;
        if (quad < 2) {
            const float4* ep = (const float4*)(esc + (e0 + row) * 16 + quad * 8);
            float4 p0 = ep[0], p1 = ep[1];
            a[0]=(short)f2us(p0.x); a[1]=(short)f2us(p0.y);
            a[2]=(short)f2us(p0.z); a[3]=(short)f2us(p0.w);
            a[4]=(short)f2us(p1.x); a[5]=(short)f2us(p1.y);
            a[6]=(short)f2us(p1.z); a[7]=(short)f2us(p1.w);
        }
#pragma unroll
        for (int nt = 0; nt < 4; nt++) {
            f32x4 c; c[0]=0.f; c[1]=0.f; c[2]=0.f; c[3]=0.f;
            c = __builtin_amdgcn_mfma_f32_16x16x32_bf16(a, bw0[nt], c, 0, 0, 0);
#pragma unroll
            for (int r = 0; r < 4; r++) {
                int edge = mt * 16 + quad * 4 + r;
                int j = nt * 16 + l15;
                Hs[edge * 68 + j] = f2us(__sinf(c[r]));
            }
        }
    }
    __syncthreads();

    f32x4 acc[4][2];
#pragma unroll
    for (int mt = 0; mt < 4; mt++)
#pragma unroll
        for (int nt = 0; nt < 2; nt++) {
            acc[mt][nt][0]=0.f; acc[mt][nt][1]=0.f;
            acc[mt][nt][2]=0.f; acc[mt][nt][3]=0.f;
        }
#pragma unroll
    for (int mt = 0; mt < 4; mt++) {
        int row = mt * 16 + l15;
        float4 eaq = ((const float4*)ea_in)[e0 + row];
#pragma unroll
        for (int kt = 0; kt < 8; kt++) {
            unsigned int hp = *(const u32a*)(Hs + row * 68 + kt * 8 + quad * 2);
            float H0 = us2f(hp & 0xFFFFu), H1 = us2f(hp >> 16);
            short8 a;
            a[0]=(short)f2us(H0*eaq.x); a[1]=(short)f2us(H0*eaq.y);
            a[2]=(short)f2us(H0*eaq.z); a[3]=(short)f2us(H0*eaq.w);
            a[4]=(short)f2us(H1*eaq.x); a[5]=(short)f2us(H1*eaq.y);
            a[6]=(short)f2us(H1*eaq.z); a[7]=(short)f2us(H1*eaq.w);
            const short8 b0 = *(const short8*)(w2p + ((kt*2+0)*64 + lane) * 8);
            const short8 b1 = *(const short8*)(w2p + ((kt*2+1)*64 + lane) * 8);
            acc[mt][0] = __builtin_amdgcn_mfma_f32_16x16x32_bf16(a, b0, acc[mt][0], 0, 0, 0);
            acc[mt][1] = __builtin_amdgcn_mfma_f32_16x16x32_bf16(a, b1, acc[mt][1], 0, 0, 0);
        }
    }
    __syncthreads();
#pragma unroll
    for (int mt = 0; mt < 4; mt++)
#pragma unroll
        for (int nt = 0; nt < 2; nt++)
#pragma unroll
            for (int r = 0; r < 4; r++)
                Ts[(mt*16 + quad*4 + r) * 34 + nt*16 + l15] = acc[mt][nt][r] * 0.125f;

    {
        long ge = e0 + lane;
        float tv[32];
#pragma unroll
        for (int u = 0; u < 32; u++) tv[u] = Ts[lane * 34 + u];
        int src = srcp[ge], pm = perm[ge];
        float4 eaq = ((const float4*)ea_in)[ge];
        float ea[4] = {eaq.x, eaq.y, eaq.z, eaq.w};
        const float4* xp = (const float4*)(xl + (long)src * 32);
        float ef[32];
#pragma unroll
        for (int g = 0; g < 8; g++) {
            float4 xq = xp[g];
            ef[4*g+0] = 0.5f * xq.x * tv[4*g+0];
            ef[4*g+1] = 0.5f * xq.y * tv[4*g+1];
            ef[4*g+2] = 0.5f * xq.z * tv[4*g+2];
            ef[4*g+3] = 0.5f * xq.w * tv[4*g+3];
        }
        uint4* efp = (uint4*)(ef_bf + (long)pm * 32);
#pragma unroll
        for (int g = 0; g < 4; g++) {
            uint4 wv;
            wv.x = (unsigned)f2us(ef[8*g+0]) | ((unsigned)f2us(ef[8*g+1]) << 16);
            wv.y = (unsigned)f2us(ef[8*g+2]) | ((unsigned)f2us(ef[8*g+3]) << 16);
            wv.z = (unsigned)f2us(ef[8*g+4]) | ((unsigned)f2us(ef[8*g+5]) << 16);
            wv.w = (unsigned)f2us(ef[8*g+6]) | ((unsigned)f2us(ef[8*g+7]) << 16);
            efp[g] = wv;
        }
        float eo[4] = {0.f, 0.f, 0.f, 0.f};
#pragma unroll
        for (int u = 0; u < 32; u++) {
            float efu = ef[u];
#pragma unroll
            for (int v = 0; v < 4; v++) {
                float p = efu * ea[v];
                const float* sw = sew + (u * 4 + v) * 4;
#pragma unroll
                for (int k = 0; k < 4; k++) eo[k] = fmaf(p, sw[k], eo[k]);
            }
        }
        constexpr float SCE_SCALE = 0.02209708691f;
        float4 o;
        o.x = ea[0] + eo[0]*SCE_SCALE; o.y = ea[1] + eo[1]*SCE_SCALE;
        o.z = ea[2] + eo[2]*SCE_SCALE; o.w = ea[3] + eo[3]*SCE_SCALE;
        ((float4*)ea_out)[ge] = o;
    }
}

// --------- gather (8 lanes/node) + node post via MFMA -----------------------
__global__ __launch_bounds__(256) void k_gpost_m(
        const int* __restrict__ off, const unsigned short* __restrict__ ef,
        const float* __restrict__ nf_cur, const float* __restrict__ nattr,
        const unsigned short* __restrict__ wnp_l,
        float* __restrict__ nf_next, float* __restrict__ out_nf, int last) {
    __shared__ f32a Xs[64 * 33];
    __shared__ f32a As[64 * 33];
    __shared__ f32a Ys[64 * 9];
    const int t = threadIdx.x;
    const long n0 = (long)blockIdx.x * 64;
    stage_xy(nf_cur, nattr, n0, t, Xs, Ys);

    {   // gather: 8 lanes/node (even/odd rows), 2 node batches
        int slot = t >> 3, g = (t >> 2) & 1, l4 = t & 3;
#pragma unroll
        for (int batch = 0; batch < 2; batch++) {
            int nl = batch * 32 + slot;
            long n = n0 + nl;
            float v[8] = {0.f,0.f,0.f,0.f,0.f,0.f,0.f,0.f};
            if (n < NN) {
                int b = off[n] + g, en = off[n + 1];
                for (int r = b; r < en; r += 2) {
                    uint4 q = *(const uint4*)(ef + (long)r * 32 + l4 * 8);
                    v[0] += us2f(q.x & 0xFFFFu); v[1] += us2f(q.x >> 16);
                    v[2] += us2f(q.y & 0xFFFFu); v[3] += us2f(q.y >> 16);
                    v[4] += us2f(q.z & 0xFFFFu); v[5] += us2f(q.z >> 16);
                    v[6] += us2f(q.w & 0xFFFFu); v[7] += us2f(q.w >> 16);
                }
            }
#pragma unroll
            for (int i = 0; i < 8; i++) v[i] += __shfl_xor(v[i], 4);
            if (g == 0) {
#pragma unroll
                for (int i = 0; i < 8; i++)
                    As[nl * 33 + l4 * 8 + i] = v[i] * 0.25f;
            }
        }
    }
    __syncthreads();

    const int lane = t & 63, w = t >> 6;
    const int l15 = lane & 15, quad = lane >> 4;
    const int nb = w * 16;
    float y[8], xk[8], ak[8];
#pragma unroll
    for (int v = 0; v < 8; v++) y[v] = Ys[(nb + l15) * 9 + v];
#pragma unroll
    for (int kt = 0; kt < 8; kt++) {
        xk[kt] = Xs[(nb + l15) * 33 + kt * 4 + quad];
        ak[kt] = As[(nb + l15) * 33 + kt * 4 + quad];
    }
    f32x4 sc0, sc1, l20, l21, al;
    sc0[0]=0.f;sc0[1]=0.f;sc0[2]=0.f;sc0[3]=0.f;
    sc1 = sc0; l20 = sc0; l21 = sc0; al = sc0;
#pragma unroll
    for (int kt = 0; kt < 8; kt++) {
        float xv = xk[kt], av = ak[kt];
        short8 ax, ag;
#pragma unroll
        for (int i = 0; i < 8; i++) {
            ax[i] = (short)f2us(xv * y[i]);
            ag[i] = (short)f2us(av * y[i]);
        }
        const short8 b2 = *(const short8*)(wnp_l + ((2 * 8 + kt) * 512) + lane * 8);
        const short8 b3 = *(const short8*)(wnp_l + ((3 * 8 + kt) * 512) + lane * 8);
        const short8 b4 = *(const short8*)(wnp_l + ((4 * 8 + kt) * 512) + lane * 8);
        const short8 b5 = *(const short8*)(wnp_l + ((5 * 8 + kt) * 512) + lane * 8);
        const short8 b6 = *(const short8*)(wnp_l + ((6 * 8 + kt) * 512) + lane * 8);
        sc0 = __builtin_amdgcn_mfma_f32_16x16x32_bf16(ax, b2, sc0, 0, 0, 0);
        sc1 = __builtin_amdgcn_mfma_f32_16x16x32_bf16(ax, b3, sc1, 0, 0, 0);
        l20 = __builtin_amdgcn_mfma_f32_16x16x32_bf16(ag, b4, l20, 0, 0, 0);
        l21 = __builtin_amdgcn_mfma_f32_16x16x32_bf16(ag, b5, l21, 0, 0, 0);
        al  = __builtin_amdgcn_mfma_f32_16x16x32_bf16(ag, b6, al,  0, 0, 0);
    }
#pragma unroll
    for (int r = 0; r < 4; r++) {
        float alpha = __shfl(al[r], quad * 16) * 0.0625f;  // col 0 of alpha tile
        long n = n0 + nb + quad * 4 + r;
        if (n < NN) {
            float o0 = sc0[r] * 0.0625f + alpha * (l20[r] * 0.0625f);
            float o1 = sc1[r] * 0.0625f + alpha * (l21[r] * 0.0625f);
            if (last) {
                out_nf[n * 32 + l15]      = o0;
                out_nf[n * 32 + 16 + l15] = o1;
            } else {
                nf_next[n * 32 + l15]      = __sinf(o0);
                nf_next[n * 32 + 16 + l15] = __sinf(o1);
            }
        }
    }
}

// ---------------------------------------------------------------------------
extern "C" void kernel_launch(void* const* d_in, const int* in_sizes, int n_in,
                              void* d_out, int out_size, void* d_ws, size_t ws_size,
                              hipStream_t stream) {
    int I_nf, I_na, I_esrc, I_edst, I_ea, I_esc, I_sc, I_l1, I_l2, I_al, I_se, I_f0, I_f1;
    if (in_sizes[0] == 1600000) {            // dict order
        I_nf=0; I_na=1; I_esrc=2; I_edst=3; I_ea=4; I_esc=5;
        I_sc=6; I_l1=7; I_l2=8; I_al=9; I_se=10; I_f0=11; I_f1=12;
    } else {                                  // sorted keys
        I_al=0; I_ea=1; I_edst=2; I_esc=3; I_esrc=4; I_f0=5; I_f1=6;
        I_l1=7; I_l2=8; I_na=9; I_nf=10; I_sc=11; I_se=12;
    }
    const float* nf_in = (const float*)d_in[I_nf];
    const float* na    = (const float*)d_in[I_na];
    const int*   esrc  = (const int*)d_in[I_esrc];
    const int*   edst  = (const int*)d_in[I_edst];
    const float* ea_in = (const float*)d_in[I_ea];
    const float* escl  = (const float*)d_in[I_esc];
    const float* w_sc  = (const float*)d_in[I_sc];
    const float* w_l1  = (const float*)d_in[I_l1];
    const float* w_l2  = (const float*)d_in[I_l2];
    const float* w_al  = (const float*)d_in[I_al];
    const float* w_se  = (const float*)d_in[I_se];
    const float* w_f0  = (const float*)d_in[I_f0];
    const float* w_f1  = (const float*)d_in[I_f1];

    float* ws = (float*)d_ws;
    float* out_nf = (float*)d_out;              // f32 [50000*32]
    float* out_ea = out_nf + (long)NN * 32;     // f32 [800000*4]

    unsigned short* w0p     = (unsigned short*)(ws + OFF_W0P);
    unsigned short* w2p     = (unsigned short*)(ws + OFF_W2P);
    unsigned short* wnp     = (unsigned short*)(ws + OFF_WNP);
    int*            csr_off = (int*)(ws + OFF_OFF);
    int*            csr_cur = (int*)(ws + OFF_CUR);
    int*            perm    = (int*)(ws + OFF_PERM);
    int*            bsum    = (int*)(ws + OFF_BSUM);
    unsigned short* ef_bf   = (unsigned short*)(ws + OFF_EF);

    hipMemsetAsync(csr_cur, 0, NN * sizeof(int), stream);
    k_hist<<<3125, 256, 0, stream>>>(edst, csr_cur, w_f0, w_f1,
                                     w_l1, w_sc, w_l2, w_al, w0p, w2p, wnp);
    k_scan1<<<SCAN_BLOCKS, 256, 0, stream>>>(csr_cur, bsum);
    k_scan2<<<1, 256, 0, stream>>>(bsum);
    k_scan3<<<SCAN_BLOCKS, 256, 0, stream>>>(csr_cur, bsum, csr_off, csr_cur);
    k_perm<<<3125, 256, 0, stream>>>(edst, csr_cur, perm);

    for (int l = 0; l < 2; l++) {
        int last = (l == 1);
        const float* nf_cur = (l == 0) ? nf_in : (ws + OFF_NF);
        const float* ea_cur = (l == 0) ? ea_in : out_ea;

        k_npre_m<<<782, 256, 0, stream>>>(nf_cur, na, wnp + l * 28672,
                                          out_nf /*xl scratch*/);
        k_edge_w<<<3125, 256, 0, stream>>>(escl, esrc, perm, ea_cur, out_ea,
                                           out_nf /*xl*/, w0p + l * 2048,
                                           w2p + l * 8192, w_se + l * 512,
                                           ef_bf);
        k_gpost_m<<<782, 256, 0, stream>>>(csr_off, ef_bf,
                                           nf_cur, na, wnp + l * 28672,
                                           ws + OFF_NF, out_nf, last);
    }
}